// Round 7
// baseline (260.137 us; speedup 1.0000x reference)
//
#include <hip/hip_runtime.h>

#define DI static __device__ __forceinline__

typedef __attribute__((ext_vector_type(8))) short s8v;
typedef __attribute__((ext_vector_type(4))) float f4v;

DI short f2b(float x) {
  unsigned u = __builtin_bit_cast(unsigned, x);
  u = (u + 0x7fffu + ((u >> 16) & 1u)) >> 16;
  return (short)u;
}
DI float b2f(short s) {
  unsigned u = ((unsigned)(unsigned short)s) << 16;
  return __builtin_bit_cast(float, u);
}
DI f4v mfma16(s8v a, s8v b, f4v c) {
  return __builtin_amdgcn_mfma_f32_16x16x32_bf16(a, b, c, 0, 0, 0);
}

// ---------------- f32 -> bf16 convert ----------------
__global__ __launch_bounds__(256) void cvt_k(const float* __restrict__ src,
                                             short* __restrict__ dst, int n) {
  int i = blockIdx.x * 256 + threadIdx.x;
  if (i < n) dst[i] = f2b(src[i]);
}

// ---------------- grouped 9x9 stride-2 conv (offset net part 1) ----------------
__global__ __launch_bounds__(256) void conv_off_k(
    const float* __restrict__ x, const float* __restrict__ y,
    const float* __restrict__ w1, const float* __restrict__ b1,
    float* __restrict__ co)
{
  __shared__ float si[8][16][84];   // 43 kB
  const int cc = blockIdx.x;        // channel chunk (8 ch)
  const int n  = blockIdx.y;        // b*4+g
  const int b = n >> 2, g = n & 3;
  const int c0 = cc * 8;
  const float* src = (g < 2 ? x : y) + ((size_t)b * 640 + (g & 1) * 320 + c0) * 512;
  const int tid = threadIdx.x;

  for (int i = tid; i < 8 * 16 * 84; i += 256) ((float*)si)[i] = 0.f;
  __syncthreads();
  for (int i = tid; i < 8 * 512; i += 256) {
    int ch = i >> 9, idx = i & 511;
    int r = idx >> 6, c = idx & 63;
    int pc = c + 4;
    si[ch][r + 4][(pc & 1) * 42 + (pc >> 1)] = src[(size_t)ch * 512 + idx];
  }
  __syncthreads();

  const int lane = tid & 63, wvi = tid >> 6;
  const int cl = lane & 15, rg = lane >> 4;
  const int ocs = __builtin_amdgcn_readfirstlane(c0 + 2 * wvi);
  const float* wbase = w1 + (size_t)ocs * 162;
  float a00 = 0.f, a01 = 0.f, a10 = 0.f, a11 = 0.f;  // [oc][col0/col1]
#pragma unroll
  for (int ic = 0; ic < 2; ++ic) {
    const float* ib = &si[2 * wvi + ic][0][0];
#pragma unroll
    for (int kh = 0; kh < 9; ++kh) {
      const int rb = (2 * rg + kh) * 84;
      float ev[6], ov[5];
#pragma unroll
      for (int t = 0; t < 6; ++t) ev[t] = ib[rb + 2 * cl + t];
#pragma unroll
      for (int t = 0; t < 5; ++t) ov[t] = ib[rb + 42 + 2 * cl + t];
      const float* wv0 = wbase + ic * 81 + kh * 9;
      const float* wv1 = wv0 + 162;
#pragma unroll
      for (int kw = 0; kw < 9; ++kw) {
        float w0 = wv0[kw], w1v = wv1[kw];
        int j = kw >> 1;
        float v0 = (kw & 1) ? ov[j] : ev[j];
        float v1 = (kw & 1) ? ov[j + 1] : ev[j + 1];
        a00 = fmaf(v0, w0, a00);
        a01 = fmaf(v1, w0, a01);
        a10 = fmaf(v0, w1v, a10);
        a11 = fmaf(v1, w1v, a11);
      }
    }
  }
  const float bv0 = b1[ocs], bv1 = b1[ocs + 1];
  const int s0 = rg * 32 + 2 * cl;
  float2 vA = {a00 + bv0, a10 + bv1};
  float2 vB = {a01 + bv0, a11 + bv1};
  *(float2*)&co[((size_t)n * 128 + s0) * 320 + ocs] = vA;
  *(float2*)&co[((size_t)n * 128 + s0 + 1) * 320 + ocs] = vB;
}

// ---------------- LN + GELU + proj + tanh -> pos (offset net part 2) ----------------
__global__ __launch_bounds__(256) void ln_proj_k(
    const float* __restrict__ co, const float* __restrict__ lng,
    const float* __restrict__ lnb, const float* __restrict__ w2,
    float* __restrict__ pos, float* __restrict__ pos_out, float* __restrict__ ref_out)
{
  const int n = blockIdx.y;
  const int wvi = threadIdx.x >> 6, lane = threadIdx.x & 63;
  const int s = blockIdx.x * 4 + wvi;
  const float* cp = co + ((size_t)n * 128 + s) * 320;
  float v[5], gw[5], gb[5], p0[5], p1[5];
#pragma unroll
  for (int t = 0; t < 5; ++t) {
    int ch = lane + 64 * t;
    v[t] = cp[ch]; gw[t] = lng[ch]; gb[t] = lnb[ch];
    p0[t] = w2[ch]; p1[t] = w2[320 + ch];
  }
  float s1 = 0.f, s2 = 0.f;
#pragma unroll
  for (int t = 0; t < 5; ++t) { s1 += v[t]; s2 += v[t] * v[t]; }
#pragma unroll
  for (int o = 32; o; o >>= 1) { s1 += __shfl_xor(s1, o); s2 += __shfl_xor(s2, o); }
  float mu = s1 * (1.f / 320.f);
  float var = s2 * (1.f / 320.f) - mu * mu;
  float rstd = rsqrtf(var + 1e-5f);
  float d0 = 0.f, d1 = 0.f;
#pragma unroll
  for (int t = 0; t < 5; ++t) {
    float xn = (v[t] - mu) * rstd * gw[t] + gb[t];
    float ge = 0.5f * xn * (1.f + erff(xn * 0.70710678118654752f));
    d0 = fmaf(ge, p0[t], d0);
    d1 = fmaf(ge, p1[t], d1);
  }
#pragma unroll
  for (int o = 32; o; o >>= 1) { d0 += __shfl_xor(d0, o); d1 += __shfl_xor(d1, o); }
  if (lane == 0) {
    float oy = tanhf(d0) * 0.5f;
    float ox = tanhf(d1) * 0.0625f;
    int hk = s >> 5, wk = s & 31;
    float ry = ((float)hk + 0.5f) * 0.5f - 1.f;
    float rx = ((float)wk + 0.5f) * 0.0625f - 1.f;
    float py = oy + ry, px = ox + rx;
    size_t o2 = ((size_t)n * 128 + s) * 2;
    pos[o2] = py;     pos[o2 + 1] = px;
    pos_out[o2] = py; pos_out[o2 + 1] = px;
    ref_out[o2] = ry; ref_out[o2 + 1] = rx;
  }
}

// ---------------- transpose [b][c][hw] f32 -> [b][hw][c] bf16 ----------------
__global__ __launch_bounds__(256) void transpose_k(const float* __restrict__ x,
                                                   short* __restrict__ xt) {
  __shared__ float tile[32][33];
  const int ct = blockIdx.x, st = blockIdx.y, b = blockIdx.z;
  const int tx = threadIdx.x, ty = threadIdx.y;
  const float* src = x + ((size_t)b * 640 + ct * 32) * 512 + st * 32;
#pragma unroll
  for (int k2 = 0; k2 < 4; ++k2)
    tile[ty + 8 * k2][tx] = src[(size_t)(ty + 8 * k2) * 512 + tx];
  __syncthreads();
  short* dst = xt + ((size_t)b * 512 + st * 32) * 640 + ct * 32;
#pragma unroll
  for (int k2 = 0; k2 < 4; ++k2)
    dst[(size_t)(ty + 8 * k2) * 640 + tx] = f2b(tile[tx][ty + 8 * k2]);
}

// ---------------- bilinear sampler: xs[b][n=128][c=640] bf16 ----------------
__global__ __launch_bounds__(256) void sample_k(const short* __restrict__ xt,
                                                const float* __restrict__ pos,
                                                short* __restrict__ xs) {
  const int sc = blockIdx.x, bg = blockIdx.y;
  const int b = bg >> 2, g = bg & 3;
  const int t = threadIdx.x;
  const int s = sc * 8 + (t >> 5);
  const int ci = t & 31;
  size_t p2 = ((size_t)bg * 128 + s) * 2;
  float py = pos[p2], px = pos[p2 + 1];
  float gx = (px + 1.f) * 32.f - 0.5f;
  float gy = (py + 1.f) * 4.f - 0.5f;
  float fx = floorf(gx), fy = floorf(gy);
  int x0 = (int)fx, y0 = (int)fy;
  float wx1 = gx - fx, wx0 = 1.f - wx1;
  float wy1 = gy - fy, wy0 = 1.f - wy1;
  int xx[2] = {x0, x0 + 1}, yy[2] = {y0, y0 + 1};
  float wxs[2] = {wx0, wx1}, wys[2] = {wy0, wy1};
  const short* basep = xt + (size_t)b * 512 * 640 + (size_t)g * 160;
  short* outp = xs + ((size_t)(b * 128 + s)) * 640 + g * 160;
#pragma unroll
  for (int kk = 0; kk < 5; ++kk) {
    int c = kk * 32 + ci;
    float acc = 0.f;
#pragma unroll
    for (int ty = 0; ty < 2; ++ty) {
      int yv = yy[ty];
      bool vy = (yv >= 0) & (yv < 8);
      int yc = min(max(yv, 0), 7);
#pragma unroll
      for (int tx = 0; tx < 2; ++tx) {
        int xv = xx[tx];
        bool vv = vy & (xv >= 0) & (xv < 64);
        int xc = min(max(xv, 0), 63);
        float val = b2f(basep[((size_t)yc * 64 + xc) * 640 + c]);
        acc += wys[ty] * wxs[tx] * (vv ? val : 0.f);
      }
    }
    outp[c] = f2b(acc);
  }
}

// ---------------- MFMA GEMM (all operands [row][K]): Out[bz][M][N] = W @ X^T + bias --
template <bool BIASN, bool OUTF32>
__global__ __launch_bounds__(256) void gemm_k(
    const short* __restrict__ W, long long wStride,
    const short* __restrict__ X, long long xStride,
    const float* __restrict__ bias, void* __restrict__ Out,
    int M, int K, int N)
{
  __shared__ short wa[64 * 64];
  __shared__ short xb[64 * 64];
  const int m0 = blockIdx.x * 64, n0 = blockIdx.y * 64;
  const int bz = blockIdx.z;
  const short* Wp = W + (size_t)bz * wStride;
  const short* Xp = X + (size_t)bz * xStride;
  const int tid = threadIdx.x;
  const int lane = tid & 63, wvi = tid >> 6;
  const int wr = wvi >> 1, wc = wvi & 1, lr = lane & 15, lg = lane >> 4;
  f4v acc[2][2];
#pragma unroll
  for (int i = 0; i < 2; ++i)
#pragma unroll
    for (int j = 0; j < 2; ++j) acc[i][j] = (f4v)0.0f;

  const int nk = K >> 5;
  for (int ks = 0; ks < nk; ++ks) {
    __syncthreads();
    {
      int m = tid >> 2, c = tid & 3;
      *(s8v*)&wa[m * 64 + ((c ^ (m & 7)) << 3)] =
          *(const s8v*)&Wp[(size_t)(m0 + m) * K + ks * 32 + c * 8];
      int n = tid >> 2;
      *(s8v*)&xb[n * 64 + ((c ^ (n & 7)) << 3)] =
          *(const s8v*)&Xp[(size_t)(n0 + n) * K + ks * 32 + c * 8];
    }
    __syncthreads();
    s8v av[2], bv[2];
#pragma unroll
    for (int i = 0; i < 2; ++i) {
      int row = wr * 32 + i * 16 + lr;
      av[i] = *(const s8v*)&wa[row * 64 + ((lg ^ (row & 7)) << 3)];
    }
#pragma unroll
    for (int j = 0; j < 2; ++j) {
      int row = wc * 32 + j * 16 + lr;
      bv[j] = *(const s8v*)&xb[row * 64 + ((lg ^ (row & 7)) << 3)];
    }
#pragma unroll
    for (int i = 0; i < 2; ++i)
#pragma unroll
      for (int j = 0; j < 2; ++j)
        acc[i][j] = mfma16(av[i], bv[j], acc[i][j]);
  }

#pragma unroll
  for (int i = 0; i < 2; ++i)
#pragma unroll
    for (int j = 0; j < 2; ++j)
#pragma unroll
      for (int r = 0; r < 4; ++r) {
        int m_g = m0 + wr * 32 + i * 16 + lg * 4 + r;
        int n_g = n0 + wc * 32 + j * 16 + lr;
        float val = acc[i][j][r] + (BIASN ? bias[n_g] : bias[m_g]);
        size_t oidx = (size_t)bz * M * N + (size_t)m_g * N + n_g;
        if (OUTF32) ((float*)Out)[oidx] = val;
        else        ((short*)Out)[oidx] = f2b(val);
      }
}

// ---------------- fused QK^T + RPE bias + softmax + PV -> ao_t (bf16) -------------
// Wave-private m-rows: wave wvi owns rows m0+wvi*16..+15 across all 128 n.
// RPE table zero-padded (+3 ring) in LDS -> branchless bilinear taps.
// grid (bh, mt): linear id % 8 == h -> all m-tiles of (b,h) on one XCD.
__global__ __launch_bounds__(256) void qkpv_k(
    const short* __restrict__ q_t, const short* __restrict__ k_t,
    const short* __restrict__ v_, const float* __restrict__ pos,
    const float* __restrict__ rpe, short* __restrict__ ao_t)
{
  __shared__ short pT[64 * 136];      // 17.4 kB
  __shared__ float rpeL[21 * 132];    // 11.1 kB, zero-padded ring of 3
  __shared__ float posL[256];
  const int bh = blockIdx.x, mt = blockIdx.y;
  const int b = bh >> 3, h = bh & 7, g = h >> 1;
  const int bg = b * 4 + g;
  const int m0 = mt * 64;
  const int tid = threadIdx.x;

  for (int i = tid; i < 21 * 132; i += 256) rpeL[i] = 0.f;
  __syncthreads();
  for (int i = tid; i < 15 * 127; i += 256) {
    int r = i / 127, c = i - r * 127;
    rpeL[(r + 3) * 132 + (c + 3)] = rpe[(size_t)h * (15 * 127) + i];
  }
  posL[tid] = pos[(size_t)bg * 256 + tid];

  const int lane = tid & 63, wvi = tid >> 6;
  const int lr = lane & 15, lg = lane >> 4;

  // ---- QK^T: wave-private 16 m-rows x 128 n, fragments from global ----
  const short* qp = q_t + ((size_t)b * 512 + m0 + wvi * 16) * 640 + h * 80;
  const short* kp = k_t + (size_t)b * 128 * 640 + h * 80;
  f4v acc[8];
#pragma unroll
  for (int j = 0; j < 8; ++j) acc[j] = (f4v)0.0f;
#pragma unroll
  for (int ks = 0; ks < 3; ++ks) {
    const int ch = (ks * 4 + lg) * 8;     // 0..88; >=80 invalid
    const bool chv = ch < 80;
    s8v av = chv ? *(const s8v*)&qp[(size_t)lr * 640 + ch] : (s8v)(short)0;
#pragma unroll
    for (int j = 0; j < 8; ++j) {
      s8v bv = chv ? *(const s8v*)&kp[(size_t)(j * 16 + lr) * 640 + ch] : (s8v)(short)0;
      acc[j] = mfma16(av, bv, acc[j]);
    }
  }
  __syncthreads();   // rpeL/posL ready (fill overlapped with MFMA)

  // ---- bias + softmax (all wave-local) ----
  float Pyn[8], Pxn[8];
#pragma unroll
  for (int j = 0; j < 8; ++j) {
    float py = posL[(j * 16 + lr) * 2], px = posL[(j * 16 + lr) * 2 + 1];
    Pyn[j] = 10.0f - py * 3.75f;
    Pxn[j] = 66.0f - px * 31.75f;
  }
  float Gy[4], Gx[4];
#pragma unroll
  for (int r = 0; r < 4; ++r) {
    int m_g = m0 + wvi * 16 + lg * 4 + r;
    float qgy = (float)(m_g >> 6) * 0.25f + (0.125f - 1.f);
    float qgx = (float)(m_g & 63) * 0.03125f + (0.015625f - 1.f);
    Gy[r] = qgy * 3.75f;
    Gx[r] = qgx * 31.75f;
  }
  const float scale = 0.11180339887498949f;  // 80^-0.5
  float mx[4] = {-1e30f, -1e30f, -1e30f, -1e30f};
#pragma unroll
  for (int j = 0; j < 8; ++j)
#pragma unroll
    for (int r = 0; r < 4; ++r) {
      float gy = Gy[r] + Pyn[j], gx = Gx[r] + Pxn[j];
      float fy = floorf(gy), fx = floorf(gx);
      int iy = (int)fy, ix = (int)fx;
      float wy = gy - fy, wx = gx - fx;
      const float* t = &rpeL[iy * 132 + ix];
      float t00 = t[0], t01 = t[1], t10 = t[132], t11 = t[133];
      float top = fmaf(wx, t01 - t00, t00);
      float bot = fmaf(wx, t11 - t10, t10);
      float bias = fmaf(wy, bot - top, top);
      float sv = fmaf(acc[j][r], scale, bias);
      acc[j][r] = sv;
      mx[r] = fmaxf(mx[r], sv);
    }
#pragma unroll
  for (int r = 0; r < 4; ++r) {
#pragma unroll
    for (int o = 8; o; o >>= 1) mx[r] = fmaxf(mx[r], __shfl_xor(mx[r], o));
  }
  float sm[4] = {0.f, 0.f, 0.f, 0.f};
#pragma unroll
  for (int j = 0; j < 8; ++j)
#pragma unroll
    for (int r = 0; r < 4; ++r) {
      float e = __expf(acc[j][r] - mx[r]);
      acc[j][r] = e;
      sm[r] += e;
    }
#pragma unroll
  for (int r = 0; r < 4; ++r) {
#pragma unroll
    for (int o = 8; o; o >>= 1) sm[r] += __shfl_xor(sm[r], o);
    sm[r] = 1.f / sm[r];
  }
  // write normalized P into wave-private pT rows (no barrier needed: same wave reads)
#pragma unroll
  for (int j = 0; j < 8; ++j)
#pragma unroll
    for (int r = 0; r < 4; ++r)
      pT[(wvi * 16 + lg * 4 + r) * 136 + j * 16 + lr] = f2b(acc[j][r] * sm[r]);

  // ---- PV: P from LDS (own rows), V fragments from global ----
  const short* vp = v_ + ((size_t)b * 640 + h * 80) * 128;
  f4v pacc[5];
#pragma unroll
  for (int t = 0; t < 5; ++t) pacc[t] = (f4v)0.0f;
#pragma unroll
  for (int ks = 0; ks < 4; ++ks) {
    s8v pa = *(const s8v*)&pT[(wvi * 16 + lr) * 136 + ks * 32 + lg * 8];
#pragma unroll
    for (int ct = 0; ct < 5; ++ct) {
      s8v vb = *(const s8v*)&vp[(size_t)(ct * 16 + lr) * 128 + ks * 32 + lg * 8];
      pacc[ct] = mfma16(pa, vb, pacc[ct]);
    }
  }
  short* aop = ao_t + ((size_t)b * 512 + m0 + wvi * 16) * 640 + h * 80;
#pragma unroll
  for (int ct = 0; ct < 5; ++ct)
#pragma unroll
    for (int r = 0; r < 4; ++r)
      aop[(size_t)(lg * 4 + r) * 640 + ct * 16 + lr] = f2b(pacc[ct][r]);
}

// =============================== launcher ===============================
extern "C" void kernel_launch(void* const* d_in, const int* in_sizes, int n_in,
                              void* d_out, int out_size, void* d_ws, size_t ws_size,
                              hipStream_t stream) {
  (void)in_sizes; (void)n_in; (void)out_size; (void)ws_size;
  const float* x   = (const float*)d_in[0];
  const float* y   = (const float*)d_in[1];
  const float* w1  = (const float*)d_in[2];
  const float* b1  = (const float*)d_in[3];
  const float* lng = (const float*)d_in[4];
  const float* lnb = (const float*)d_in[5];
  const float* w2  = (const float*)d_in[6];
  const float* qw  = (const float*)d_in[7];
  const float* qb  = (const float*)d_in[8];
  const float* kw  = (const float*)d_in[9];
  const float* kb  = (const float*)d_in[10];
  const float* vw  = (const float*)d_in[11];
  const float* vb  = (const float*)d_in[12];
  const float* ow  = (const float*)d_in[13];
  const float* ob  = (const float*)d_in[14];
  const float* rpe = (const float*)d_in[15];
  float* out = (float*)d_out;
  float* pos_out = out + 10485760;
  float* ref_out = out + 10518528;

  char* base = (char*)d_ws;
  size_t off = 0;
  auto take = [&](size_t bytes) {
    char* pch = base + off;
    off = (off + bytes + 255) & ~(size_t)255;
    return pch;
  };
  float* pos   = (float*)take(131072);        // [128][128][2] f32
  short* x_t   = (short*)take(20971520);      // [32][512][640] bf16
  short* y_t   = (short*)take(20971520);      // [32][512][640] bf16
  short* q_t   = (short*)take(20971520);      // [32][512][640] bf16
  short* qw_bf = (short*)take(819200);
  short* kw_bf = (short*)take(819200);
  short* vw_bf = (short*)take(819200);
  short* ow_bf = (short*)take(819200);
  short* xs_bf = (short*)take(5242880);       // [32][128][640] bf16
  short* k_t   = (short*)take(5242880);       // [32][128][640] bf16
  short* v_bf  = (short*)take(5242880);       // [32][640][128] bf16
  char*  regB  = take(20971520);              // co (f32 [128][128][320]) then ao_t
  float* co    = (float*)regB;
  short* ao_t  = (short*)regB;                // [32][512][640] bf16

  // transposes + weight converts
  transpose_k<<<dim3(20, 16, 32), dim3(32, 8), 0, stream>>>(x, x_t);
  transpose_k<<<dim3(20, 16, 32), dim3(32, 8), 0, stream>>>(y, y_t);
  cvt_k<<<1600, 256, 0, stream>>>(qw, qw_bf, 409600);
  cvt_k<<<1600, 256, 0, stream>>>(kw, kw_bf, 409600);
  cvt_k<<<1600, 256, 0, stream>>>(vw, vw_bf, 409600);
  cvt_k<<<1600, 256, 0, stream>>>(ow, ow_bf, 409600);

  // offset network
  conv_off_k<<<dim3(40, 128), 256, 0, stream>>>(x, y, w1, b1, co);
  ln_proj_k<<<dim3(32, 128), 256, 0, stream>>>(co, lng, lnb, w2, pos, pos_out, ref_out);

  // deformable sampling
  sample_k<<<dim3(16, 128), 256, 0, stream>>>(x_t, pos, xs_bf);

  // projections (all [row][K] GEMMs)
  gemm_k<true,  false><<<dim3(8, 10, 32), 256, 0, stream>>>(y_t, 512LL * 640, qw_bf, 0LL, qb, q_t, 512, 640, 640);
  gemm_k<true,  false><<<dim3(2, 10, 32), 256, 0, stream>>>(xs_bf, 128LL * 640, kw_bf, 0LL, kb, k_t, 128, 640, 640);
  gemm_k<false, false><<<dim3(10, 2, 32), 256, 0, stream>>>(vw_bf, 0LL, xs_bf, 128LL * 640, vb, v_bf, 640, 640, 128);

  // fused attention (QK^T + bias + softmax + PV)
  qkpv_k<<<dim3(256, 8), 256, 0, stream>>>(q_t, k_t, v_bf, pos, rpe, ao_t);

  // output projection (f32 out)
  gemm_k<false, true><<<dim3(10, 8, 32), 256, 0, stream>>>(ow_bf, 0LL, ao_t, 512LL * 640, ob, out, 640, 640, 512);
}

// Round 8
// 252.953 us; speedup vs baseline: 1.0284x; 1.0284x over previous
//
#include <hip/hip_runtime.h>

#define DI static __device__ __forceinline__

typedef __attribute__((ext_vector_type(8))) short s8v;
typedef __attribute__((ext_vector_type(4))) float f4v;

DI short f2b(float x) {
  unsigned u = __builtin_bit_cast(unsigned, x);
  u = (u + 0x7fffu + ((u >> 16) & 1u)) >> 16;
  return (short)u;
}
DI float b2f(short s) {
  unsigned u = ((unsigned)(unsigned short)s) << 16;
  return __builtin_bit_cast(float, u);
}
DI f4v mfma16(s8v a, s8v b, f4v c) {
  return __builtin_amdgcn_mfma_f32_16x16x32_bf16(a, b, c, 0, 0, 0);
}

// ---------------- f32 -> bf16 convert ----------------
__global__ __launch_bounds__(256) void cvt_k(const float* __restrict__ src,
                                             short* __restrict__ dst, int n) {
  int i = blockIdx.x * 256 + threadIdx.x;
  if (i < n) dst[i] = f2b(src[i]);
}

// ---------------- grouped 9x9 stride-2 conv (offset net part 1) ----------------
__global__ __launch_bounds__(256) void conv_off_k(
    const float* __restrict__ x, const float* __restrict__ y,
    const float* __restrict__ w1, const float* __restrict__ b1,
    float* __restrict__ co)
{
  __shared__ float si[8][16][84];   // 43 kB
  const int cc = blockIdx.x;        // channel chunk (8 ch)
  const int n  = blockIdx.y;        // b*4+g
  const int b = n >> 2, g = n & 3;
  const int c0 = cc * 8;
  const float* src = (g < 2 ? x : y) + ((size_t)b * 640 + (g & 1) * 320 + c0) * 512;
  const int tid = threadIdx.x;

  for (int i = tid; i < 8 * 16 * 84; i += 256) ((float*)si)[i] = 0.f;
  __syncthreads();
  for (int i = tid; i < 8 * 512; i += 256) {
    int ch = i >> 9, idx = i & 511;
    int r = idx >> 6, c = idx & 63;
    int pc = c + 4;
    si[ch][r + 4][(pc & 1) * 42 + (pc >> 1)] = src[(size_t)ch * 512 + idx];
  }
  __syncthreads();

  const int lane = tid & 63, wvi = tid >> 6;
  const int cl = lane & 15, rg = lane >> 4;
  const int ocs = __builtin_amdgcn_readfirstlane(c0 + 2 * wvi);
  const float* wbase = w1 + (size_t)ocs * 162;
  float a00 = 0.f, a01 = 0.f, a10 = 0.f, a11 = 0.f;  // [oc][col0/col1]
#pragma unroll
  for (int ic = 0; ic < 2; ++ic) {
    const float* ib = &si[2 * wvi + ic][0][0];
#pragma unroll
    for (int kh = 0; kh < 9; ++kh) {
      const int rb = (2 * rg + kh) * 84;
      float ev[6], ov[5];
#pragma unroll
      for (int t = 0; t < 6; ++t) ev[t] = ib[rb + 2 * cl + t];
#pragma unroll
      for (int t = 0; t < 5; ++t) ov[t] = ib[rb + 42 + 2 * cl + t];
      const float* wv0 = wbase + ic * 81 + kh * 9;
      const float* wv1 = wv0 + 162;
#pragma unroll
      for (int kw = 0; kw < 9; ++kw) {
        float w0 = wv0[kw], w1v = wv1[kw];
        int j = kw >> 1;
        float v0 = (kw & 1) ? ov[j] : ev[j];
        float v1 = (kw & 1) ? ov[j + 1] : ev[j + 1];
        a00 = fmaf(v0, w0, a00);
        a01 = fmaf(v1, w0, a01);
        a10 = fmaf(v0, w1v, a10);
        a11 = fmaf(v1, w1v, a11);
      }
    }
  }
  const float bv0 = b1[ocs], bv1 = b1[ocs + 1];
  const int s0 = rg * 32 + 2 * cl;
  float2 vA = {a00 + bv0, a10 + bv1};
  float2 vB = {a01 + bv0, a11 + bv1};
  *(float2*)&co[((size_t)n * 128 + s0) * 320 + ocs] = vA;
  *(float2*)&co[((size_t)n * 128 + s0 + 1) * 320 + ocs] = vB;
}

// ---------------- LN + GELU + proj + tanh -> pos (offset net part 2) ----------------
__global__ __launch_bounds__(256) void ln_proj_k(
    const float* __restrict__ co, const float* __restrict__ lng,
    const float* __restrict__ lnb, const float* __restrict__ w2,
    float* __restrict__ pos, float* __restrict__ pos_out, float* __restrict__ ref_out)
{
  const int n = blockIdx.y;
  const int wvi = threadIdx.x >> 6, lane = threadIdx.x & 63;
  const int s = blockIdx.x * 4 + wvi;
  const float* cp = co + ((size_t)n * 128 + s) * 320;
  float v[5], gw[5], gb[5], p0[5], p1[5];
#pragma unroll
  for (int t = 0; t < 5; ++t) {
    int ch = lane + 64 * t;
    v[t] = cp[ch]; gw[t] = lng[ch]; gb[t] = lnb[ch];
    p0[t] = w2[ch]; p1[t] = w2[320 + ch];
  }
  float s1 = 0.f, s2 = 0.f;
#pragma unroll
  for (int t = 0; t < 5; ++t) { s1 += v[t]; s2 += v[t] * v[t]; }
#pragma unroll
  for (int o = 32; o; o >>= 1) { s1 += __shfl_xor(s1, o); s2 += __shfl_xor(s2, o); }
  float mu = s1 * (1.f / 320.f);
  float var = s2 * (1.f / 320.f) - mu * mu;
  float rstd = rsqrtf(var + 1e-5f);
  float d0 = 0.f, d1 = 0.f;
#pragma unroll
  for (int t = 0; t < 5; ++t) {
    float xn = (v[t] - mu) * rstd * gw[t] + gb[t];
    float ge = 0.5f * xn * (1.f + erff(xn * 0.70710678118654752f));
    d0 = fmaf(ge, p0[t], d0);
    d1 = fmaf(ge, p1[t], d1);
  }
#pragma unroll
  for (int o = 32; o; o >>= 1) { d0 += __shfl_xor(d0, o); d1 += __shfl_xor(d1, o); }
  if (lane == 0) {
    float oy = tanhf(d0) * 0.5f;
    float ox = tanhf(d1) * 0.0625f;
    int hk = s >> 5, wk = s & 31;
    float ry = ((float)hk + 0.5f) * 0.5f - 1.f;
    float rx = ((float)wk + 0.5f) * 0.0625f - 1.f;
    float py = oy + ry, px = ox + rx;
    size_t o2 = ((size_t)n * 128 + s) * 2;
    pos[o2] = py;     pos[o2 + 1] = px;
    pos_out[o2] = py; pos_out[o2 + 1] = px;
    ref_out[o2] = ry; ref_out[o2 + 1] = rx;
  }
}

// ---------------- transpose [b][c][hw] f32 -> [b][hw][c] bf16 ----------------
__global__ __launch_bounds__(256) void transpose_k(const float* __restrict__ x,
                                                   short* __restrict__ xt) {
  __shared__ float tile[32][33];
  const int ct = blockIdx.x, st = blockIdx.y, b = blockIdx.z;
  const int tx = threadIdx.x, ty = threadIdx.y;
  const float* src = x + ((size_t)b * 640 + ct * 32) * 512 + st * 32;
#pragma unroll
  for (int k2 = 0; k2 < 4; ++k2)
    tile[ty + 8 * k2][tx] = src[(size_t)(ty + 8 * k2) * 512 + tx];
  __syncthreads();
  short* dst = xt + ((size_t)b * 512 + st * 32) * 640 + ct * 32;
#pragma unroll
  for (int k2 = 0; k2 < 4; ++k2)
    dst[(size_t)(ty + 8 * k2) * 640 + tx] = f2b(tile[tx][ty + 8 * k2]);
}

// ---------------- bilinear sampler: xs[b][n=128][c=640] bf16 ----------------
__global__ __launch_bounds__(256) void sample_k(const short* __restrict__ xt,
                                                const float* __restrict__ pos,
                                                short* __restrict__ xs) {
  const int sc = blockIdx.x, bg = blockIdx.y;
  const int b = bg >> 2, g = bg & 3;
  const int t = threadIdx.x;
  const int s = sc * 8 + (t >> 5);
  const int ci = t & 31;
  size_t p2 = ((size_t)bg * 128 + s) * 2;
  float py = pos[p2], px = pos[p2 + 1];
  float gx = (px + 1.f) * 32.f - 0.5f;
  float gy = (py + 1.f) * 4.f - 0.5f;
  float fx = floorf(gx), fy = floorf(gy);
  int x0 = (int)fx, y0 = (int)fy;
  float wx1 = gx - fx, wx0 = 1.f - wx1;
  float wy1 = gy - fy, wy0 = 1.f - wy1;
  int xx[2] = {x0, x0 + 1}, yy[2] = {y0, y0 + 1};
  float wxs[2] = {wx0, wx1}, wys[2] = {wy0, wy1};
  const short* basep = xt + (size_t)b * 512 * 640 + (size_t)g * 160;
  short* outp = xs + ((size_t)(b * 128 + s)) * 640 + g * 160;
#pragma unroll
  for (int kk = 0; kk < 5; ++kk) {
    int c = kk * 32 + ci;
    float acc = 0.f;
#pragma unroll
    for (int ty = 0; ty < 2; ++ty) {
      int yv = yy[ty];
      bool vy = (yv >= 0) & (yv < 8);
      int yc = min(max(yv, 0), 7);
#pragma unroll
      for (int tx = 0; tx < 2; ++tx) {
        int xv = xx[tx];
        bool vv = vy & (xv >= 0) & (xv < 64);
        int xc = min(max(xv, 0), 63);
        float val = b2f(basep[((size_t)yc * 64 + xc) * 640 + c]);
        acc += wys[ty] * wxs[tx] * (vv ? val : 0.f);
      }
    }
    outp[c] = f2b(acc);
  }
}

// ---------------- MFMA GEMM (all operands [row][K]): Out[bz][M][N] = W @ X^T + bias --
template <bool BIASN, bool OUTF32>
__global__ __launch_bounds__(256) void gemm_k(
    const short* __restrict__ W, long long wStride,
    const short* __restrict__ X, long long xStride,
    const float* __restrict__ bias, void* __restrict__ Out,
    int M, int K, int N)
{
  __shared__ short wa[64 * 64];
  __shared__ short xb[64 * 64];
  const int m0 = blockIdx.x * 64, n0 = blockIdx.y * 64;
  const int bz = blockIdx.z;
  const short* Wp = W + (size_t)bz * wStride;
  const short* Xp = X + (size_t)bz * xStride;
  const int tid = threadIdx.x;
  const int lane = tid & 63, wvi = tid >> 6;
  const int wr = wvi >> 1, wc = wvi & 1, lr = lane & 15, lg = lane >> 4;
  f4v acc[2][2];
#pragma unroll
  for (int i = 0; i < 2; ++i)
#pragma unroll
    for (int j = 0; j < 2; ++j) acc[i][j] = (f4v)0.0f;

  const int nk = K >> 5;
  for (int ks = 0; ks < nk; ++ks) {
    __syncthreads();
    {
      int m = tid >> 2, c = tid & 3;
      *(s8v*)&wa[m * 64 + ((c ^ (m & 7)) << 3)] =
          *(const s8v*)&Wp[(size_t)(m0 + m) * K + ks * 32 + c * 8];
      int n = tid >> 2;
      *(s8v*)&xb[n * 64 + ((c ^ (n & 7)) << 3)] =
          *(const s8v*)&Xp[(size_t)(n0 + n) * K + ks * 32 + c * 8];
    }
    __syncthreads();
    s8v av[2], bv[2];
#pragma unroll
    for (int i = 0; i < 2; ++i) {
      int row = wr * 32 + i * 16 + lr;
      av[i] = *(const s8v*)&wa[row * 64 + ((lg ^ (row & 7)) << 3)];
    }
#pragma unroll
    for (int j = 0; j < 2; ++j) {
      int row = wc * 32 + j * 16 + lr;
      bv[j] = *(const s8v*)&xb[row * 64 + ((lg ^ (row & 7)) << 3)];
    }
#pragma unroll
    for (int i = 0; i < 2; ++i)
#pragma unroll
      for (int j = 0; j < 2; ++j)
        acc[i][j] = mfma16(av[i], bv[j], acc[i][j]);
  }

#pragma unroll
  for (int i = 0; i < 2; ++i)
#pragma unroll
    for (int j = 0; j < 2; ++j)
#pragma unroll
      for (int r = 0; r < 4; ++r) {
        int m_g = m0 + wr * 32 + i * 16 + lg * 4 + r;
        int n_g = n0 + wc * 32 + j * 16 + lr;
        float val = acc[i][j][r] + (BIASN ? bias[n_g] : bias[m_g]);
        size_t oidx = (size_t)bz * M * N + (size_t)m_g * N + n_g;
        if (OUTF32) ((float*)Out)[oidx] = val;
        else        ((short*)Out)[oidx] = f2b(val);
      }
}

// ---------------- fused QK^T + RPE bias + softmax + PV -> ao_t (bf16) -------------
// R6 balanced 2x4 wave split (6 fragment loads per ks) + zero-padded RPE table
// + affine-hoisted bias sampling. grid (bh, mt) for XCD locality.
__global__ __launch_bounds__(256) void qkpv_k(
    const short* __restrict__ q_t, const short* __restrict__ k_t,
    const short* __restrict__ v_, const float* __restrict__ pos,
    const float* __restrict__ rpe, short* __restrict__ ao_t)
{
  __shared__ short pT[64 * 136];      // 17.4 kB
  __shared__ float rpeL[21 * 132];    // 11.1 kB, zero-padded ring of 3
  __shared__ float posL[256];
  __shared__ float redA[2][64];
  __shared__ float redB[2][64];
  const int bh = blockIdx.x, mt = blockIdx.y;
  const int b = bh >> 3, h = bh & 7, g = h >> 1;
  const int bg = b * 4 + g;
  const int m0 = mt * 64;
  const int tid = threadIdx.x;

  for (int i = tid; i < 21 * 132; i += 256) rpeL[i] = 0.f;
  __syncthreads();
  for (int i = tid; i < 15 * 127; i += 256) {
    int r = i / 127, c = i - r * 127;
    rpeL[(r + 3) * 132 + (c + 3)] = rpe[(size_t)h * (15 * 127) + i];
  }
  posL[tid] = pos[(size_t)bg * 256 + tid];

  const int lane = tid & 63, wvi = tid >> 6;
  const int wr = wvi >> 1, wc = wvi & 1, lr = lane & 15, lg = lane >> 4;

  // ---- QK^T: fragments straight from global (balanced 2 Q + 4 K loads/ks) ----
  const short* qp = q_t + ((size_t)b * 512 + m0) * 640 + h * 80;
  const short* kp = k_t + (size_t)b * 128 * 640 + h * 80;
  f4v acc[2][4];
#pragma unroll
  for (int i = 0; i < 2; ++i)
#pragma unroll
    for (int j = 0; j < 4; ++j) acc[i][j] = (f4v)0.0f;

#pragma unroll
  for (int ks = 0; ks < 3; ++ks) {
    const int ch = (ks * 4 + lg) * 8;     // 0..88; >=80 invalid
    const bool chv = ch < 80;
    s8v av[2], bv[4];
#pragma unroll
    for (int i = 0; i < 2; ++i) {
      int row = wr * 32 + i * 16 + lr;
      av[i] = chv ? *(const s8v*)&qp[(size_t)row * 640 + ch] : (s8v)(short)0;
    }
#pragma unroll
    for (int j = 0; j < 4; ++j) {
      int row = wc * 64 + j * 16 + lr;
      bv[j] = chv ? *(const s8v*)&kp[(size_t)row * 640 + ch] : (s8v)(short)0;
    }
#pragma unroll
    for (int i = 0; i < 2; ++i)
#pragma unroll
      for (int j = 0; j < 4; ++j)
        acc[i][j] = mfma16(av[i], bv[j], acc[i][j]);
  }
  __syncthreads();   // rpeL/posL ready (fill overlapped with MFMA)

  // ---- bias (affine + padded table) + row max ----
  float Pyn[4], Pxn[4];
#pragma unroll
  for (int j = 0; j < 4; ++j) {
    int n_l = wc * 64 + j * 16 + lr;
    float py = posL[n_l * 2], px = posL[n_l * 2 + 1];
    Pyn[j] = 10.0f - py * 3.75f;
    Pxn[j] = 66.0f - px * 31.75f;
  }
  float Gy[2][4], Gx[2][4];
#pragma unroll
  for (int i = 0; i < 2; ++i)
#pragma unroll
    for (int r = 0; r < 4; ++r) {
      int m_g = m0 + wr * 32 + i * 16 + lg * 4 + r;
      float qgy = (float)(m_g >> 6) * 0.25f + (0.125f - 1.f);
      float qgx = (float)(m_g & 63) * 0.03125f + (0.015625f - 1.f);
      Gy[i][r] = qgy * 3.75f;
      Gx[i][r] = qgx * 31.75f;
    }
  const float scale = 0.11180339887498949f;  // 80^-0.5
  float rmax[2][4];
#pragma unroll
  for (int i = 0; i < 2; ++i)
#pragma unroll
    for (int r = 0; r < 4; ++r) {
      float mxv = -1e30f;
#pragma unroll
      for (int j = 0; j < 4; ++j) {
        float gy = Gy[i][r] + Pyn[j], gx = Gx[i][r] + Pxn[j];
        float fy = floorf(gy), fx = floorf(gx);
        int iy = (int)fy, ix = (int)fx;
        float wy = gy - fy, wx = gx - fx;
        const float* t = &rpeL[iy * 132 + ix];
        float t00 = t[0], t01 = t[1], t10 = t[132], t11 = t[133];
        float top = fmaf(wx, t01 - t00, t00);
        float bot = fmaf(wx, t11 - t10, t10);
        float bias = fmaf(wy, bot - top, top);
        float sv = fmaf(acc[i][j][r], scale, bias);
        acc[i][j][r] = sv;
        mxv = fmaxf(mxv, sv);
      }
#pragma unroll
      for (int o = 8; o; o >>= 1) mxv = fmaxf(mxv, __shfl_xor(mxv, o));
      rmax[i][r] = mxv;
    }
  if (lr == 0) {
#pragma unroll
    for (int i = 0; i < 2; ++i)
#pragma unroll
      for (int r = 0; r < 4; ++r)
        redA[wc][wr * 32 + i * 16 + lg * 4 + r] = rmax[i][r];
  }
  __syncthreads();
  float rsum[2][4];
#pragma unroll
  for (int i = 0; i < 2; ++i)
#pragma unroll
    for (int r = 0; r < 4; ++r) {
      int row = wr * 32 + i * 16 + lg * 4 + r;
      float mfull = fmaxf(redA[0][row], redA[1][row]);
      float sm = 0.f;
#pragma unroll
      for (int j = 0; j < 4; ++j) {
        float e = __expf(acc[i][j][r] - mfull);
        acc[i][j][r] = e;
        sm += e;
      }
#pragma unroll
      for (int o = 8; o; o >>= 1) sm += __shfl_xor(sm, o);
      rsum[i][r] = sm;
    }
  if (lr == 0) {
#pragma unroll
    for (int i = 0; i < 2; ++i)
#pragma unroll
      for (int r = 0; r < 4; ++r)
        redB[wc][wr * 32 + i * 16 + lg * 4 + r] = rsum[i][r];
  }
  __syncthreads();
  // write normalized P (bf16) into pT
#pragma unroll
  for (int i = 0; i < 2; ++i)
#pragma unroll
    for (int r = 0; r < 4; ++r) {
      int row = wr * 32 + i * 16 + lg * 4 + r;
      float inv = 1.f / (redB[0][row] + redB[1][row]);
#pragma unroll
      for (int j = 0; j < 4; ++j) {
        int n_l = wc * 64 + j * 16 + lr;
        pT[row * 136 + n_l] = f2b(acc[i][j][r] * inv);
      }
    }
  __syncthreads();

  // ---- PV: P from LDS, V fragments straight from global ----
  const short* vp = v_ + ((size_t)b * 640 + h * 80) * 128;
  f4v pacc[5];
#pragma unroll
  for (int t = 0; t < 5; ++t) pacc[t] = (f4v)0.0f;
#pragma unroll
  for (int ks = 0; ks < 4; ++ks) {
    s8v pa = *(const s8v*)&pT[(wvi * 16 + lr) * 136 + ks * 32 + lg * 8];
#pragma unroll
    for (int ct = 0; ct < 5; ++ct) {
      s8v vb = *(const s8v*)&vp[(size_t)(ct * 16 + lr) * 128 + ks * 32 + lg * 8];
      pacc[ct] = mfma16(pa, vb, pacc[ct]);
    }
  }
  short* aop = ao_t + ((size_t)b * 512 + m0 + wvi * 16) * 640 + h * 80;
#pragma unroll
  for (int ct = 0; ct < 5; ++ct)
#pragma unroll
    for (int r = 0; r < 4; ++r)
      aop[(size_t)(lg * 4 + r) * 640 + ct * 16 + lr] = f2b(pacc[ct][r]);
}

// =============================== launcher ===============================
extern "C" void kernel_launch(void* const* d_in, const int* in_sizes, int n_in,
                              void* d_out, int out_size, void* d_ws, size_t ws_size,
                              hipStream_t stream) {
  (void)in_sizes; (void)n_in; (void)out_size; (void)ws_size;
  const float* x   = (const float*)d_in[0];
  const float* y   = (const float*)d_in[1];
  const float* w1  = (const float*)d_in[2];
  const float* b1  = (const float*)d_in[3];
  const float* lng = (const float*)d_in[4];
  const float* lnb = (const float*)d_in[5];
  const float* w2  = (const float*)d_in[6];
  const float* qw  = (const float*)d_in[7];
  const float* qb  = (const float*)d_in[8];
  const float* kw  = (const float*)d_in[9];
  const float* kb  = (const float*)d_in[10];
  const float* vw  = (const float*)d_in[11];
  const float* vb  = (const float*)d_in[12];
  const float* ow  = (const float*)d_in[13];
  const float* ob  = (const float*)d_in[14];
  const float* rpe = (const float*)d_in[15];
  float* out = (float*)d_out;
  float* pos_out = out + 10485760;
  float* ref_out = out + 10518528;

  char* base = (char*)d_ws;
  size_t off = 0;
  auto take = [&](size_t bytes) {
    char* pch = base + off;
    off = (off + bytes + 255) & ~(size_t)255;
    return pch;
  };
  float* pos   = (float*)take(131072);        // [128][128][2] f32
  short* x_t   = (short*)take(20971520);      // [32][512][640] bf16
  short* y_t   = (short*)take(20971520);      // [32][512][640] bf16
  short* q_t   = (short*)take(20971520);      // [32][512][640] bf16
  short* qw_bf = (short*)take(819200);
  short* kw_bf = (short*)take(819200);
  short* vw_bf = (short*)take(819200);
  short* ow_bf = (short*)take(819200);
  short* xs_bf = (short*)take(5242880);       // [32][128][640] bf16
  short* k_t   = (short*)take(5242880);       // [32][128][640] bf16
  short* v_bf  = (short*)take(5242880);       // [32][640][128] bf16
  char*  regB  = take(20971520);              // co (f32 [128][128][320]) then ao_t
  float* co    = (float*)regB;
  short* ao_t  = (short*)regB;                // [32][512][640] bf16

  // transposes + weight converts
  transpose_k<<<dim3(20, 16, 32), dim3(32, 8), 0, stream>>>(x, x_t);
  transpose_k<<<dim3(20, 16, 32), dim3(32, 8), 0, stream>>>(y, y_t);
  cvt_k<<<1600, 256, 0, stream>>>(qw, qw_bf, 409600);
  cvt_k<<<1600, 256, 0, stream>>>(kw, kw_bf, 409600);
  cvt_k<<<1600, 256, 0, stream>>>(vw, vw_bf, 409600);
  cvt_k<<<1600, 256, 0, stream>>>(ow, ow_bf, 409600);

  // offset network
  conv_off_k<<<dim3(40, 128), 256, 0, stream>>>(x, y, w1, b1, co);
  ln_proj_k<<<dim3(32, 128), 256, 0, stream>>>(co, lng, lnb, w2, pos, pos_out, ref_out);

  // deformable sampling
  sample_k<<<dim3(16, 128), 256, 0, stream>>>(x_t, pos, xs_bf);

  // projections (all [row][K] GEMMs)
  gemm_k<true,  false><<<dim3(8, 10, 32), 256, 0, stream>>>(y_t, 512LL * 640, qw_bf, 0LL, qb, q_t, 512, 640, 640);
  gemm_k<true,  false><<<dim3(2, 10, 32), 256, 0, stream>>>(xs_bf, 128LL * 640, kw_bf, 0LL, kb, k_t, 128, 640, 640);
  gemm_k<false, false><<<dim3(10, 2, 32), 256, 0, stream>>>(vw_bf, 0LL, xs_bf, 128LL * 640, vb, v_bf, 640, 640, 128);

  // fused attention (QK^T + bias + softmax + PV)
  qkpv_k<<<dim3(256, 8), 256, 0, stream>>>(q_t, k_t, v_bf, pos, rpe, ao_t);

  // output projection (f32 out)
  gemm_k<false, true><<<dim3(10, 8, 32), 256, 0, stream>>>(ow_bf, 0LL, ao_t, 512LL * 640, ob, out, 640, 640, 512);
}

// Round 9
// 237.687 us; speedup vs baseline: 1.0945x; 1.0642x over previous
//
#include <hip/hip_runtime.h>

#define DI static __device__ __forceinline__

typedef __attribute__((ext_vector_type(8))) short s8v;
typedef __attribute__((ext_vector_type(4))) float f4v;

DI short f2b(float x) {
  unsigned u = __builtin_bit_cast(unsigned, x);
  u = (u + 0x7fffu + ((u >> 16) & 1u)) >> 16;
  return (short)u;
}
DI float b2f(short s) {
  unsigned u = ((unsigned)(unsigned short)s) << 16;
  return __builtin_bit_cast(float, u);
}
DI f4v mfma16(s8v a, s8v b, f4v c) {
  return __builtin_amdgcn_mfma_f32_16x16x32_bf16(a, b, c, 0, 0, 0);
}
DI void gload16(const short* g, short* l) {
  __builtin_amdgcn_global_load_lds(
      (const __attribute__((address_space(1))) unsigned*)g,
      (__attribute__((address_space(3))) unsigned*)l, 16, 0, 0);
}

// ---------------- f32 -> bf16 convert ----------------
__global__ __launch_bounds__(256) void cvt_k(const float* __restrict__ src,
                                             short* __restrict__ dst, int n) {
  int i = blockIdx.x * 256 + threadIdx.x;
  if (i < n) dst[i] = f2b(src[i]);
}

// ---------------- grouped 9x9 stride-2 conv (offset net part 1) ----------------
__global__ __launch_bounds__(256) void conv_off_k(
    const float* __restrict__ x, const float* __restrict__ y,
    const float* __restrict__ w1, const float* __restrict__ b1,
    float* __restrict__ co)
{
  __shared__ float si[8][16][84];   // 43 kB
  const int cc = blockIdx.x;        // channel chunk (8 ch)
  const int n  = blockIdx.y;        // b*4+g
  const int b = n >> 2, g = n & 3;
  const int c0 = cc * 8;
  const float* src = (g < 2 ? x : y) + ((size_t)b * 640 + (g & 1) * 320 + c0) * 512;
  const int tid = threadIdx.x;

  for (int i = tid; i < 8 * 16 * 84; i += 256) ((float*)si)[i] = 0.f;
  __syncthreads();
  for (int i = tid; i < 8 * 512; i += 256) {
    int ch = i >> 9, idx = i & 511;
    int r = idx >> 6, c = idx & 63;
    int pc = c + 4;
    si[ch][r + 4][(pc & 1) * 42 + (pc >> 1)] = src[(size_t)ch * 512 + idx];
  }
  __syncthreads();

  const int lane = tid & 63, wvi = tid >> 6;
  const int cl = lane & 15, rg = lane >> 4;
  const int ocs = __builtin_amdgcn_readfirstlane(c0 + 2 * wvi);
  const float* wbase = w1 + (size_t)ocs * 162;
  float a00 = 0.f, a01 = 0.f, a10 = 0.f, a11 = 0.f;  // [oc][col0/col1]
#pragma unroll
  for (int ic = 0; ic < 2; ++ic) {
    const float* ib = &si[2 * wvi + ic][0][0];
#pragma unroll
    for (int kh = 0; kh < 9; ++kh) {
      const int rb = (2 * rg + kh) * 84;
      float ev[6], ov[5];
#pragma unroll
      for (int t = 0; t < 6; ++t) ev[t] = ib[rb + 2 * cl + t];
#pragma unroll
      for (int t = 0; t < 5; ++t) ov[t] = ib[rb + 42 + 2 * cl + t];
      const float* wv0 = wbase + ic * 81 + kh * 9;
      const float* wv1 = wv0 + 162;
#pragma unroll
      for (int kw = 0; kw < 9; ++kw) {
        float w0 = wv0[kw], w1v = wv1[kw];
        int j = kw >> 1;
        float v0 = (kw & 1) ? ov[j] : ev[j];
        float v1 = (kw & 1) ? ov[j + 1] : ev[j + 1];
        a00 = fmaf(v0, w0, a00);
        a01 = fmaf(v1, w0, a01);
        a10 = fmaf(v0, w1v, a10);
        a11 = fmaf(v1, w1v, a11);
      }
    }
  }
  const float bv0 = b1[ocs], bv1 = b1[ocs + 1];
  const int s0 = rg * 32 + 2 * cl;
  float2 vA = {a00 + bv0, a10 + bv1};
  float2 vB = {a01 + bv0, a11 + bv1};
  *(float2*)&co[((size_t)n * 128 + s0) * 320 + ocs] = vA;
  *(float2*)&co[((size_t)n * 128 + s0 + 1) * 320 + ocs] = vB;
}

// ---------------- LN + GELU + proj + tanh -> pos (offset net part 2) ----------------
__global__ __launch_bounds__(256) void ln_proj_k(
    const float* __restrict__ co, const float* __restrict__ lng,
    const float* __restrict__ lnb, const float* __restrict__ w2,
    float* __restrict__ pos, float* __restrict__ pos_out, float* __restrict__ ref_out)
{
  const int n = blockIdx.y;
  const int wvi = threadIdx.x >> 6, lane = threadIdx.x & 63;
  const int s = blockIdx.x * 4 + wvi;
  const float* cp = co + ((size_t)n * 128 + s) * 320;
  float v[5], gw[5], gb[5], p0[5], p1[5];
#pragma unroll
  for (int t = 0; t < 5; ++t) {
    int ch = lane + 64 * t;
    v[t] = cp[ch]; gw[t] = lng[ch]; gb[t] = lnb[ch];
    p0[t] = w2[ch]; p1[t] = w2[320 + ch];
  }
  float s1 = 0.f, s2 = 0.f;
#pragma unroll
  for (int t = 0; t < 5; ++t) { s1 += v[t]; s2 += v[t] * v[t]; }
#pragma unroll
  for (int o = 32; o; o >>= 1) { s1 += __shfl_xor(s1, o); s2 += __shfl_xor(s2, o); }
  float mu = s1 * (1.f / 320.f);
  float var = s2 * (1.f / 320.f) - mu * mu;
  float rstd = rsqrtf(var + 1e-5f);
  float d0 = 0.f, d1 = 0.f;
#pragma unroll
  for (int t = 0; t < 5; ++t) {
    float xn = (v[t] - mu) * rstd * gw[t] + gb[t];
    float ge = 0.5f * xn * (1.f + erff(xn * 0.70710678118654752f));
    d0 = fmaf(ge, p0[t], d0);
    d1 = fmaf(ge, p1[t], d1);
  }
#pragma unroll
  for (int o = 32; o; o >>= 1) { d0 += __shfl_xor(d0, o); d1 += __shfl_xor(d1, o); }
  if (lane == 0) {
    float oy = tanhf(d0) * 0.5f;
    float ox = tanhf(d1) * 0.0625f;
    int hk = s >> 5, wk = s & 31;
    float ry = ((float)hk + 0.5f) * 0.5f - 1.f;
    float rx = ((float)wk + 0.5f) * 0.0625f - 1.f;
    float py = oy + ry, px = ox + rx;
    size_t o2 = ((size_t)n * 128 + s) * 2;
    pos[o2] = py;     pos[o2 + 1] = px;
    pos_out[o2] = py; pos_out[o2 + 1] = px;
    ref_out[o2] = ry; ref_out[o2 + 1] = rx;
  }
}

// ---------------- transpose [b][c][hw] f32 -> [b][hw][c] bf16 ----------------
__global__ __launch_bounds__(256) void transpose_k(const float* __restrict__ x,
                                                   short* __restrict__ xt) {
  __shared__ float tile[32][33];
  const int ct = blockIdx.x, st = blockIdx.y, b = blockIdx.z;
  const int tx = threadIdx.x, ty = threadIdx.y;
  const float* src = x + ((size_t)b * 640 + ct * 32) * 512 + st * 32;
#pragma unroll
  for (int k2 = 0; k2 < 4; ++k2)
    tile[ty + 8 * k2][tx] = src[(size_t)(ty + 8 * k2) * 512 + tx];
  __syncthreads();
  short* dst = xt + ((size_t)b * 512 + st * 32) * 640 + ct * 32;
#pragma unroll
  for (int k2 = 0; k2 < 4; ++k2)
    dst[(size_t)(ty + 8 * k2) * 640 + tx] = f2b(tile[tx][ty + 8 * k2]);
}

// ---------------- bilinear sampler: xs[b][n=128][c=640] bf16 ----------------
__global__ __launch_bounds__(256) void sample_k(const short* __restrict__ xt,
                                                const float* __restrict__ pos,
                                                short* __restrict__ xs) {
  const int sc = blockIdx.x, bg = blockIdx.y;
  const int b = bg >> 2, g = bg & 3;
  const int t = threadIdx.x;
  const int s = sc * 8 + (t >> 5);
  const int ci = t & 31;
  size_t p2 = ((size_t)bg * 128 + s) * 2;
  float py = pos[p2], px = pos[p2 + 1];
  float gx = (px + 1.f) * 32.f - 0.5f;
  float gy = (py + 1.f) * 4.f - 0.5f;
  float fx = floorf(gx), fy = floorf(gy);
  int x0 = (int)fx, y0 = (int)fy;
  float wx1 = gx - fx, wx0 = 1.f - wx1;
  float wy1 = gy - fy, wy0 = 1.f - wy1;
  int xx[2] = {x0, x0 + 1}, yy[2] = {y0, y0 + 1};
  float wxs[2] = {wx0, wx1}, wys[2] = {wy0, wy1};
  const short* basep = xt + (size_t)b * 512 * 640 + (size_t)g * 160;
  short* outp = xs + ((size_t)(b * 128 + s)) * 640 + g * 160;
#pragma unroll
  for (int kk = 0; kk < 5; ++kk) {
    int c = kk * 32 + ci;
    float acc = 0.f;
#pragma unroll
    for (int ty = 0; ty < 2; ++ty) {
      int yv = yy[ty];
      bool vy = (yv >= 0) & (yv < 8);
      int yc = min(max(yv, 0), 7);
#pragma unroll
      for (int tx = 0; tx < 2; ++tx) {
        int xv = xx[tx];
        bool vv = vy & (xv >= 0) & (xv < 64);
        int xc = min(max(xv, 0), 63);
        float val = b2f(basep[((size_t)yc * 64 + xc) * 640 + c]);
        acc += wys[ty] * wxs[tx] * (vv ? val : 0.f);
      }
    }
    outp[c] = f2b(acc);
  }
}

// ---------------- 128x128-tile MFMA GEMM with global_load_lds (m97 structure) ----
// Out[bz][M][N] = W @ X^T + bias. W: [bz][M][K], X: [bz][N][K]. M,N % 128 == 0, K % 32 == 0.
// 4 waves in 2x2; 64x64 per wave; BK=32. LDS linear [128][32] bf16 per operand.
template <bool BIASN, bool OUTF32>
__global__ __launch_bounds__(256) void gemm128_k(
    const short* __restrict__ W, long long wStride,
    const short* __restrict__ X, long long xStride,
    const float* __restrict__ bias, void* __restrict__ Out,
    int M, int K, int N)
{
  __shared__ short wa[128 * 32];
  __shared__ short xb[128 * 32];
  const int m0 = blockIdx.x * 128, n0 = blockIdx.y * 128;
  const int bz = blockIdx.z;
  const short* Wp = W + (size_t)bz * wStride + (size_t)m0 * K;
  const short* Xp = X + (size_t)bz * xStride + (size_t)n0 * K;
  const int tid = threadIdx.x;
  const int lane = tid & 63;
  const int wvi = __builtin_amdgcn_readfirstlane(tid >> 6);
  const int wr = wvi >> 1, wc = wvi & 1, lr = lane & 15, lg = lane >> 4;

  // staging addresses: issue i in {0,1}, wave wvi -> rows (i*4+wvi)*16 .. +15
  const int r0 = (wvi * 16) + (lane >> 2);        // issue 0 row
  const int cb = (lane & 3) * 8;                  // k-offset (shorts)
  const short* wg0 = Wp + (size_t)r0 * K + cb;
  const short* wg1 = Wp + (size_t)(r0 + 64) * K + cb;
  const short* xg0 = Xp + (size_t)r0 * K + cb;
  const short* xg1 = Xp + (size_t)(r0 + 64) * K + cb;
  short* la0 = &wa[wvi * 512];
  short* la1 = &wa[(4 + wvi) * 512];
  short* lb0 = &xb[wvi * 512];
  short* lb1 = &xb[(4 + wvi) * 512];

  f4v acc[4][4];
#pragma unroll
  for (int i = 0; i < 4; ++i)
#pragma unroll
    for (int j = 0; j < 4; ++j) acc[i][j] = (f4v)0.0f;

  const int nk = K >> 5;
  for (int ks = 0; ks < nk; ++ks) {
    __syncthreads();
    const int ko = ks * 32;
    gload16(wg0 + ko, la0);
    gload16(wg1 + ko, la1);
    gload16(xg0 + ko, lb0);
    gload16(xg1 + ko, lb1);
    __syncthreads();
    s8v av[4], bv[4];
#pragma unroll
    for (int i = 0; i < 4; ++i)
      av[i] = *(const s8v*)&wa[(wr * 64 + i * 16 + lr) * 32 + lg * 8];
#pragma unroll
    for (int j = 0; j < 4; ++j)
      bv[j] = *(const s8v*)&xb[(wc * 64 + j * 16 + lr) * 32 + lg * 8];
#pragma unroll
    for (int i = 0; i < 4; ++i)
#pragma unroll
      for (int j = 0; j < 4; ++j)
        acc[i][j] = mfma16(av[i], bv[j], acc[i][j]);
  }

#pragma unroll
  for (int i = 0; i < 4; ++i)
#pragma unroll
    for (int j = 0; j < 4; ++j)
#pragma unroll
      for (int r = 0; r < 4; ++r) {
        int m_g = m0 + wr * 64 + i * 16 + lg * 4 + r;
        int n_g = n0 + wc * 64 + j * 16 + lr;
        float val = acc[i][j][r] + (BIASN ? bias[n_g] : bias[m_g]);
        size_t oidx = (size_t)bz * M * N + (size_t)m_g * N + n_g;
        if (OUTF32) ((float*)Out)[oidx] = val;
        else        ((short*)Out)[oidx] = f2b(val);
      }
}

// ---------------- fused QK^T + RPE bias + softmax + PV -> ao_t (bf16) -------------
__global__ __launch_bounds__(256) void qkpv_k(
    const short* __restrict__ q_t, const short* __restrict__ k_t,
    const short* __restrict__ v_, const float* __restrict__ pos,
    const float* __restrict__ rpe, short* __restrict__ ao_t)
{
  __shared__ short pT[64 * 136];      // 17.4 kB
  __shared__ float rpeL[21 * 132];    // 11.1 kB, zero-padded ring of 3
  __shared__ float posL[256];
  __shared__ float redA[2][64];
  __shared__ float redB[2][64];
  const int bh = blockIdx.x, mt = blockIdx.y;
  const int b = bh >> 3, h = bh & 7, g = h >> 1;
  const int bg = b * 4 + g;
  const int m0 = mt * 64;
  const int tid = threadIdx.x;

  for (int i = tid; i < 21 * 132; i += 256) rpeL[i] = 0.f;
  __syncthreads();
  for (int i = tid; i < 15 * 127; i += 256) {
    int r = i / 127, c = i - r * 127;
    rpeL[(r + 3) * 132 + (c + 3)] = rpe[(size_t)h * (15 * 127) + i];
  }
  posL[tid] = pos[(size_t)bg * 256 + tid];

  const int lane = tid & 63, wvi = tid >> 6;
  const int wr = wvi >> 1, wc = wvi & 1, lr = lane & 15, lg = lane >> 4;

  // ---- QK^T: fragments straight from global (balanced 2 Q + 4 K loads/ks) ----
  const short* qp = q_t + ((size_t)b * 512 + m0) * 640 + h * 80;
  const short* kp = k_t + (size_t)b * 128 * 640 + h * 80;
  f4v acc[2][4];
#pragma unroll
  for (int i = 0; i < 2; ++i)
#pragma unroll
    for (int j = 0; j < 4; ++j) acc[i][j] = (f4v)0.0f;

#pragma unroll
  for (int ks = 0; ks < 3; ++ks) {
    const int ch = (ks * 4 + lg) * 8;     // 0..88; >=80 invalid
    const bool chv = ch < 80;
    s8v av[2], bv[4];
#pragma unroll
    for (int i = 0; i < 2; ++i) {
      int row = wr * 32 + i * 16 + lr;
      av[i] = chv ? *(const s8v*)&qp[(size_t)row * 640 + ch] : (s8v)(short)0;
    }
#pragma unroll
    for (int j = 0; j < 4; ++j) {
      int row = wc * 64 + j * 16 + lr;
      bv[j] = chv ? *(const s8v*)&kp[(size_t)row * 640 + ch] : (s8v)(short)0;
    }
#pragma unroll
    for (int i = 0; i < 2; ++i)
#pragma unroll
      for (int j = 0; j < 4; ++j)
        acc[i][j] = mfma16(av[i], bv[j], acc[i][j]);
  }
  __syncthreads();   // rpeL/posL ready (fill overlapped with MFMA)

  // ---- bias (affine + padded table) + row max ----
  float Pyn[4], Pxn[4];
#pragma unroll
  for (int j = 0; j < 4; ++j) {
    int n_l = wc * 64 + j * 16 + lr;
    float py = posL[n_l * 2], px = posL[n_l * 2 + 1];
    Pyn[j] = 10.0f - py * 3.75f;
    Pxn[j] = 66.0f - px * 31.75f;
  }
  float Gy[2][4], Gx[2][4];
#pragma unroll
  for (int i = 0; i < 2; ++i)
#pragma unroll
    for (int r = 0; r < 4; ++r) {
      int m_g = m0 + wr * 32 + i * 16 + lg * 4 + r;
      float qgy = (float)(m_g >> 6) * 0.25f + (0.125f - 1.f);
      float qgx = (float)(m_g & 63) * 0.03125f + (0.015625f - 1.f);
      Gy[i][r] = qgy * 3.75f;
      Gx[i][r] = qgx * 31.75f;
    }
  const float scale = 0.11180339887498949f;  // 80^-0.5
  float rmax[2][4];
#pragma unroll
  for (int i = 0; i < 2; ++i)
#pragma unroll
    for (int r = 0; r < 4; ++r) {
      float mxv = -1e30f;
#pragma unroll
      for (int j = 0; j < 4; ++j) {
        float gy = Gy[i][r] + Pyn[j], gx = Gx[i][r] + Pxn[j];
        float fy = floorf(gy), fx = floorf(gx);
        int iy = (int)fy, ix = (int)fx;
        float wy = gy - fy, wx = gx - fx;
        const float* t = &rpeL[iy * 132 + ix];
        float t00 = t[0], t01 = t[1], t10 = t[132], t11 = t[133];
        float top = fmaf(wx, t01 - t00, t00);
        float bot = fmaf(wx, t11 - t10, t10);
        float bias = fmaf(wy, bot - top, top);
        float sv = fmaf(acc[i][j][r], scale, bias);
        acc[i][j][r] = sv;
        mxv = fmaxf(mxv, sv);
      }
#pragma unroll
      for (int o = 8; o; o >>= 1) mxv = fmaxf(mxv, __shfl_xor(mxv, o));
      rmax[i][r] = mxv;
    }
  if (lr == 0) {
#pragma unroll
    for (int i = 0; i < 2; ++i)
#pragma unroll
      for (int r = 0; r < 4; ++r)
        redA[wc][wr * 32 + i * 16 + lg * 4 + r] = rmax[i][r];
  }
  __syncthreads();
  float rsum[2][4];
#pragma unroll
  for (int i = 0; i < 2; ++i)
#pragma unroll
    for (int r = 0; r < 4; ++r) {
      int row = wr * 32 + i * 16 + lg * 4 + r;
      float mfull = fmaxf(redA[0][row], redA[1][row]);
      float sm = 0.f;
#pragma unroll
      for (int j = 0; j < 4; ++j) {
        float e = __expf(acc[i][j][r] - mfull);
        acc[i][j][r] = e;
        sm += e;
      }
#pragma unroll
      for (int o = 8; o; o >>= 1) sm += __shfl_xor(sm, o);
      rsum[i][r] = sm;
    }
  if (lr == 0) {
#pragma unroll
    for (int i = 0; i < 2; ++i)
#pragma unroll
      for (int r = 0; r < 4; ++r)
        redB[wc][wr * 32 + i * 16 + lg * 4 + r] = rsum[i][r];
  }
  __syncthreads();
  // write normalized P (bf16) into pT
#pragma unroll
  for (int i = 0; i < 2; ++i)
#pragma unroll
    for (int r = 0; r < 4; ++r) {
      int row = wr * 32 + i * 16 + lg * 4 + r;
      float inv = 1.f / (redB[0][row] + redB[1][row]);
#pragma unroll
      for (int j = 0; j < 4; ++j) {
        int n_l = wc * 64 + j * 16 + lr;
        pT[row * 136 + n_l] = f2b(acc[i][j][r] * inv);
      }
    }
  __syncthreads();

  // ---- PV: P from LDS, V fragments straight from global ----
  const short* vp = v_ + ((size_t)b * 640 + h * 80) * 128;
  f4v pacc[5];
#pragma unroll
  for (int t = 0; t < 5; ++t) pacc[t] = (f4v)0.0f;
#pragma unroll
  for (int ks = 0; ks < 4; ++ks) {
    s8v pa = *(const s8v*)&pT[(wvi * 16 + lr) * 136 + ks * 32 + lg * 8];
#pragma unroll
    for (int ct = 0; ct < 5; ++ct) {
      s8v vb = *(const s8v*)&vp[(size_t)(ct * 16 + lr) * 128 + ks * 32 + lg * 8];
      pacc[ct] = mfma16(pa, vb, pacc[ct]);
    }
  }
  short* aop = ao_t + ((size_t)b * 512 + m0 + wvi * 16) * 640 + h * 80;
#pragma unroll
  for (int ct = 0; ct < 5; ++ct)
#pragma unroll
    for (int r = 0; r < 4; ++r)
      aop[(size_t)(lg * 4 + r) * 640 + ct * 16 + lr] = f2b(pacc[ct][r]);
}

// =============================== launcher ===============================
extern "C" void kernel_launch(void* const* d_in, const int* in_sizes, int n_in,
                              void* d_out, int out_size, void* d_ws, size_t ws_size,
                              hipStream_t stream) {
  (void)in_sizes; (void)n_in; (void)out_size; (void)ws_size;
  const float* x   = (const float*)d_in[0];
  const float* y   = (const float*)d_in[1];
  const float* w1  = (const float*)d_in[2];
  const float* b1  = (const float*)d_in[3];
  const float* lng = (const float*)d_in[4];
  const float* lnb = (const float*)d_in[5];
  const float* w2  = (const float*)d_in[6];
  const float* qw  = (const float*)d_in[7];
  const float* qb  = (const float*)d_in[8];
  const float* kw  = (const float*)d_in[9];
  const float* kb  = (const float*)d_in[10];
  const float* vw  = (const float*)d_in[11];
  const float* vb  = (const float*)d_in[12];
  const float* ow  = (const float*)d_in[13];
  const float* ob  = (const float*)d_in[14];
  const float* rpe = (const float*)d_in[15];
  float* out = (float*)d_out;
  float* pos_out = out + 10485760;
  float* ref_out = out + 10518528;

  char* base = (char*)d_ws;
  size_t off = 0;
  auto take = [&](size_t bytes) {
    char* pch = base + off;
    off = (off + bytes + 255) & ~(size_t)255;
    return pch;
  };
  float* pos   = (float*)take(131072);        // [128][128][2] f32
  short* x_t   = (short*)take(20971520);      // [32][512][640] bf16
  short* y_t   = (short*)take(20971520);      // [32][512][640] bf16
  short* q_t   = (short*)take(20971520);      // [32][512][640] bf16
  short* qw_bf = (short*)take(819200);
  short* kw_bf = (short*)take(819200);
  short* vw_bf = (short*)take(819200);
  short* ow_bf = (short*)take(819200);
  short* xs_bf = (short*)take(5242880);       // [32][128][640] bf16
  short* k_t   = (short*)take(5242880);       // [32][128][640] bf16
  short* v_bf  = (short*)take(5242880);       // [32][640][128] bf16
  char*  regB  = take(20971520);              // co (f32 [128][128][320]) then ao_t
  float* co    = (float*)regB;
  short* ao_t  = (short*)regB;                // [32][512][640] bf16

  // transposes + weight converts
  transpose_k<<<dim3(20, 16, 32), dim3(32, 8), 0, stream>>>(x, x_t);
  transpose_k<<<dim3(20, 16, 32), dim3(32, 8), 0, stream>>>(y, y_t);
  cvt_k<<<1600, 256, 0, stream>>>(qw, qw_bf, 409600);
  cvt_k<<<1600, 256, 0, stream>>>(kw, kw_bf, 409600);
  cvt_k<<<1600, 256, 0, stream>>>(vw, vw_bf, 409600);
  cvt_k<<<1600, 256, 0, stream>>>(ow, ow_bf, 409600);

  // offset network
  conv_off_k<<<dim3(40, 128), 256, 0, stream>>>(x, y, w1, b1, co);
  ln_proj_k<<<dim3(32, 128), 256, 0, stream>>>(co, lng, lnb, w2, pos, pos_out, ref_out);

  // deformable sampling
  sample_k<<<dim3(16, 128), 256, 0, stream>>>(x_t, pos, xs_bf);

  // projections (128^2-tile global_load_lds GEMMs; all operands [row][K])
  gemm128_k<true,  false><<<dim3(4, 5, 32), 256, 0, stream>>>(y_t, 512LL * 640, qw_bf, 0LL, qb, q_t, 512, 640, 640);
  gemm128_k<true,  false><<<dim3(1, 5, 32), 256, 0, stream>>>(xs_bf, 128LL * 640, kw_bf, 0LL, kb, k_t, 128, 640, 640);
  gemm128_k<false, false><<<dim3(5, 1, 32), 256, 0, stream>>>(vw_bf, 0LL, xs_bf, 128LL * 640, vb, v_bf, 640, 640, 128);

  // fused attention (QK^T + bias + softmax + PV)
  qkpv_k<<<dim3(256, 8), 256, 0, stream>>>(q_t, k_t, v_bf, pos, rpe, ao_t);

  // output projection (f32 out)
  gemm128_k<false, true><<<dim3(5, 4, 32), 256, 0, stream>>>(ow_bf, 0LL, ao_t, 512LL * 640, ob, out, 640, 640, 512);
}

// Round 10
// 229.879 us; speedup vs baseline: 1.1316x; 1.0340x over previous
//
#include <hip/hip_runtime.h>

#define DI static __device__ __forceinline__

typedef __attribute__((ext_vector_type(8))) short s8v;
typedef __attribute__((ext_vector_type(4))) float f4v;

DI short f2b(float x) {
  unsigned u = __builtin_bit_cast(unsigned, x);
  u = (u + 0x7fffu + ((u >> 16) & 1u)) >> 16;
  return (short)u;
}
DI float b2f(short s) {
  unsigned u = ((unsigned)(unsigned short)s) << 16;
  return __builtin_bit_cast(float, u);
}
DI f4v mfma16(s8v a, s8v b, f4v c) {
  return __builtin_amdgcn_mfma_f32_16x16x32_bf16(a, b, c, 0, 0, 0);
}
DI void gload16(const short* g, short* l) {
  __builtin_amdgcn_global_load_lds(
      (const __attribute__((address_space(1))) unsigned*)g,
      (__attribute__((address_space(3))) unsigned*)l, 16, 0, 0);
}

// ---------------- f32 -> bf16 convert ----------------
__global__ __launch_bounds__(256) void cvt_k(const float* __restrict__ src,
                                             short* __restrict__ dst, int n) {
  int i = blockIdx.x * 256 + threadIdx.x;
  if (i < n) dst[i] = f2b(src[i]);
}

// ---------------- grouped 9x9 stride-2 conv (offset net part 1) ----------------
__global__ __launch_bounds__(256) void conv_off_k(
    const float* __restrict__ x, const float* __restrict__ y,
    const float* __restrict__ w1, const float* __restrict__ b1,
    float* __restrict__ co)
{
  __shared__ float si[8][16][84];   // 43 kB
  const int cc = blockIdx.x;        // channel chunk (8 ch)
  const int n  = blockIdx.y;        // b*4+g
  const int b = n >> 2, g = n & 3;
  const int c0 = cc * 8;
  const float* src = (g < 2 ? x : y) + ((size_t)b * 640 + (g & 1) * 320 + c0) * 512;
  const int tid = threadIdx.x;

  for (int i = tid; i < 8 * 16 * 84; i += 256) ((float*)si)[i] = 0.f;
  __syncthreads();
  for (int i = tid; i < 8 * 512; i += 256) {
    int ch = i >> 9, idx = i & 511;
    int r = idx >> 6, c = idx & 63;
    int pc = c + 4;
    si[ch][r + 4][(pc & 1) * 42 + (pc >> 1)] = src[(size_t)ch * 512 + idx];
  }
  __syncthreads();

  const int lane = tid & 63, wvi = tid >> 6;
  const int cl = lane & 15, rg = lane >> 4;
  const int ocs = __builtin_amdgcn_readfirstlane(c0 + 2 * wvi);
  const float* wbase = w1 + (size_t)ocs * 162;
  float a00 = 0.f, a01 = 0.f, a10 = 0.f, a11 = 0.f;  // [oc][col0/col1]
#pragma unroll
  for (int ic = 0; ic < 2; ++ic) {
    const float* ib = &si[2 * wvi + ic][0][0];
#pragma unroll
    for (int kh = 0; kh < 9; ++kh) {
      const int rb = (2 * rg + kh) * 84;
      float ev[6], ov[5];
#pragma unroll
      for (int t = 0; t < 6; ++t) ev[t] = ib[rb + 2 * cl + t];
#pragma unroll
      for (int t = 0; t < 5; ++t) ov[t] = ib[rb + 42 + 2 * cl + t];
      const float* wv0 = wbase + ic * 81 + kh * 9;
      const float* wv1 = wv0 + 162;
#pragma unroll
      for (int kw = 0; kw < 9; ++kw) {
        float w0 = wv0[kw], w1v = wv1[kw];
        int j = kw >> 1;
        float v0 = (kw & 1) ? ov[j] : ev[j];
        float v1 = (kw & 1) ? ov[j + 1] : ev[j + 1];
        a00 = fmaf(v0, w0, a00);
        a01 = fmaf(v1, w0, a01);
        a10 = fmaf(v0, w1v, a10);
        a11 = fmaf(v1, w1v, a11);
      }
    }
  }
  const float bv0 = b1[ocs], bv1 = b1[ocs + 1];
  const int s0 = rg * 32 + 2 * cl;
  float2 vA = {a00 + bv0, a10 + bv1};
  float2 vB = {a01 + bv0, a11 + bv1};
  *(float2*)&co[((size_t)n * 128 + s0) * 320 + ocs] = vA;
  *(float2*)&co[((size_t)n * 128 + s0 + 1) * 320 + ocs] = vB;
}

// ---------------- LN + GELU + proj + tanh -> pos (offset net part 2) ----------------
__global__ __launch_bounds__(256) void ln_proj_k(
    const float* __restrict__ co, const float* __restrict__ lng,
    const float* __restrict__ lnb, const float* __restrict__ w2,
    float* __restrict__ pos, float* __restrict__ pos_out, float* __restrict__ ref_out)
{
  const int n = blockIdx.y;
  const int wvi = threadIdx.x >> 6, lane = threadIdx.x & 63;
  const int s = blockIdx.x * 4 + wvi;
  const float* cp = co + ((size_t)n * 128 + s) * 320;
  float v[5], gw[5], gb[5], p0[5], p1[5];
#pragma unroll
  for (int t = 0; t < 5; ++t) {
    int ch = lane + 64 * t;
    v[t] = cp[ch]; gw[t] = lng[ch]; gb[t] = lnb[ch];
    p0[t] = w2[ch]; p1[t] = w2[320 + ch];
  }
  float s1 = 0.f, s2 = 0.f;
#pragma unroll
  for (int t = 0; t < 5; ++t) { s1 += v[t]; s2 += v[t] * v[t]; }
#pragma unroll
  for (int o = 32; o; o >>= 1) { s1 += __shfl_xor(s1, o); s2 += __shfl_xor(s2, o); }
  float mu = s1 * (1.f / 320.f);
  float var = s2 * (1.f / 320.f) - mu * mu;
  float rstd = rsqrtf(var + 1e-5f);
  float d0 = 0.f, d1 = 0.f;
#pragma unroll
  for (int t = 0; t < 5; ++t) {
    float xn = (v[t] - mu) * rstd * gw[t] + gb[t];
    float ge = 0.5f * xn * (1.f + erff(xn * 0.70710678118654752f));
    d0 = fmaf(ge, p0[t], d0);
    d1 = fmaf(ge, p1[t], d1);
  }
#pragma unroll
  for (int o = 32; o; o >>= 1) { d0 += __shfl_xor(d0, o); d1 += __shfl_xor(d1, o); }
  if (lane == 0) {
    float oy = tanhf(d0) * 0.5f;
    float ox = tanhf(d1) * 0.0625f;
    int hk = s >> 5, wk = s & 31;
    float ry = ((float)hk + 0.5f) * 0.5f - 1.f;
    float rx = ((float)wk + 0.5f) * 0.0625f - 1.f;
    float py = oy + ry, px = ox + rx;
    size_t o2 = ((size_t)n * 128 + s) * 2;
    pos[o2] = py;     pos[o2 + 1] = px;
    pos_out[o2] = py; pos_out[o2 + 1] = px;
    ref_out[o2] = ry; ref_out[o2 + 1] = rx;
  }
}

// ---------------- transpose [b][c][hw] f32 -> [b][hw][c] bf16 ----------------
__global__ __launch_bounds__(256) void transpose_k(const float* __restrict__ x,
                                                   short* __restrict__ xt) {
  __shared__ float tile[32][33];
  const int ct = blockIdx.x, st = blockIdx.y, b = blockIdx.z;
  const int tx = threadIdx.x, ty = threadIdx.y;
  const float* src = x + ((size_t)b * 640 + ct * 32) * 512 + st * 32;
#pragma unroll
  for (int k2 = 0; k2 < 4; ++k2)
    tile[ty + 8 * k2][tx] = src[(size_t)(ty + 8 * k2) * 512 + tx];
  __syncthreads();
  short* dst = xt + ((size_t)b * 512 + st * 32) * 640 + ct * 32;
#pragma unroll
  for (int k2 = 0; k2 < 4; ++k2)
    dst[(size_t)(ty + 8 * k2) * 640 + tx] = f2b(tile[tx][ty + 8 * k2]);
}

// ---------------- bilinear sampler: xs[b][n=128][c=640] bf16 ----------------
__global__ __launch_bounds__(256) void sample_k(const short* __restrict__ xt,
                                                const float* __restrict__ pos,
                                                short* __restrict__ xs) {
  const int sc = blockIdx.x, bg = blockIdx.y;
  const int b = bg >> 2, g = bg & 3;
  const int t = threadIdx.x;
  const int s = sc * 8 + (t >> 5);
  const int ci = t & 31;
  size_t p2 = ((size_t)bg * 128 + s) * 2;
  float py = pos[p2], px = pos[p2 + 1];
  float gx = (px + 1.f) * 32.f - 0.5f;
  float gy = (py + 1.f) * 4.f - 0.5f;
  float fx = floorf(gx), fy = floorf(gy);
  int x0 = (int)fx, y0 = (int)fy;
  float wx1 = gx - fx, wx0 = 1.f - wx1;
  float wy1 = gy - fy, wy0 = 1.f - wy1;
  int xx[2] = {x0, x0 + 1}, yy[2] = {y0, y0 + 1};
  float wxs[2] = {wx0, wx1}, wys[2] = {wy0, wy1};
  const short* basep = xt + (size_t)b * 512 * 640 + (size_t)g * 160;
  short* outp = xs + ((size_t)(b * 128 + s)) * 640 + g * 160;
#pragma unroll
  for (int kk = 0; kk < 5; ++kk) {
    int c = kk * 32 + ci;
    float acc = 0.f;
#pragma unroll
    for (int ty = 0; ty < 2; ++ty) {
      int yv = yy[ty];
      bool vy = (yv >= 0) & (yv < 8);
      int yc = min(max(yv, 0), 7);
#pragma unroll
      for (int tx = 0; tx < 2; ++tx) {
        int xv = xx[tx];
        bool vv = vy & (xv >= 0) & (xv < 64);
        int xc = min(max(xv, 0), 63);
        float val = b2f(basep[((size_t)yc * 64 + xc) * 640 + c]);
        acc += wys[ty] * wxs[tx] * (vv ? val : 0.f);
      }
    }
    outp[c] = f2b(acc);
  }
}

// ---------------- 128x128-tile MFMA GEMM with global_load_lds (m97 structure) ----
template <bool BIASN, bool OUTF32>
__global__ __launch_bounds__(256) void gemm128_k(
    const short* __restrict__ W, long long wStride,
    const short* __restrict__ X, long long xStride,
    const float* __restrict__ bias, void* __restrict__ Out,
    int M, int K, int N)
{
  __shared__ short wa[128 * 32];
  __shared__ short xb[128 * 32];
  const int m0 = blockIdx.x * 128, n0 = blockIdx.y * 128;
  const int bz = blockIdx.z;
  const short* Wp = W + (size_t)bz * wStride + (size_t)m0 * K;
  const short* Xp = X + (size_t)bz * xStride + (size_t)n0 * K;
  const int tid = threadIdx.x;
  const int lane = tid & 63;
  const int wvi = __builtin_amdgcn_readfirstlane(tid >> 6);
  const int wr = wvi >> 1, wc = wvi & 1, lr = lane & 15, lg = lane >> 4;

  const int r0 = (wvi * 16) + (lane >> 2);
  const int cb = (lane & 3) * 8;
  const short* wg0 = Wp + (size_t)r0 * K + cb;
  const short* wg1 = Wp + (size_t)(r0 + 64) * K + cb;
  const short* xg0 = Xp + (size_t)r0 * K + cb;
  const short* xg1 = Xp + (size_t)(r0 + 64) * K + cb;
  short* la0 = &wa[wvi * 512];
  short* la1 = &wa[(4 + wvi) * 512];
  short* lb0 = &xb[wvi * 512];
  short* lb1 = &xb[(4 + wvi) * 512];

  f4v acc[4][4];
#pragma unroll
  for (int i = 0; i < 4; ++i)
#pragma unroll
    for (int j = 0; j < 4; ++j) acc[i][j] = (f4v)0.0f;

  const int nk = K >> 5;
  for (int ks = 0; ks < nk; ++ks) {
    __syncthreads();
    const int ko = ks * 32;
    gload16(wg0 + ko, la0);
    gload16(wg1 + ko, la1);
    gload16(xg0 + ko, lb0);
    gload16(xg1 + ko, lb1);
    __syncthreads();
    s8v av[4], bv[4];
#pragma unroll
    for (int i = 0; i < 4; ++i)
      av[i] = *(const s8v*)&wa[(wr * 64 + i * 16 + lr) * 32 + lg * 8];
#pragma unroll
    for (int j = 0; j < 4; ++j)
      bv[j] = *(const s8v*)&xb[(wc * 64 + j * 16 + lr) * 32 + lg * 8];
#pragma unroll
    for (int i = 0; i < 4; ++i)
#pragma unroll
      for (int j = 0; j < 4; ++j)
        acc[i][j] = mfma16(av[i], bv[j], acc[i][j]);
  }

#pragma unroll
  for (int i = 0; i < 4; ++i)
#pragma unroll
    for (int j = 0; j < 4; ++j)
#pragma unroll
      for (int r = 0; r < 4; ++r) {
        int m_g = m0 + wr * 64 + i * 16 + lg * 4 + r;
        int n_g = n0 + wc * 64 + j * 16 + lr;
        float val = acc[i][j][r] + (BIASN ? bias[n_g] : bias[m_g]);
        size_t oidx = (size_t)bz * M * N + (size_t)m_g * N + n_g;
        if (OUTF32) ((float*)Out)[oidx] = val;
        else        ((short*)Out)[oidx] = f2b(val);
      }
}

// ---------------- fused QK^T + RPE bias + softmax + PV -> ao_t (bf16) -------------
// Block = (b,h,mh): 4 m-tiles. K/V/rpe staged in LDS ONCE; wave-private softmax;
// barrier-free main loop. kT zero-padded (cols 80..103) so B-fragments are unguarded.
__global__ __launch_bounds__(256) void qkpv_k(
    const short* __restrict__ q_t, const short* __restrict__ k_t,
    const short* __restrict__ v_, const float* __restrict__ pos,
    const float* __restrict__ rpe, short* __restrict__ ao_t)
{
  __shared__ short kT[128 * 104];     // 26.6 kB, stride 104 (2-way-free)
  __shared__ short vT[80 * 136];      // 21.8 kB, stride 136
  __shared__ short pT[64 * 136];      // 17.4 kB (wave-private quarters)
  __shared__ float rpeL[21 * 132];    // 11.1 kB, zero-padded ring of 3
  __shared__ float posL[256];
  const int bh = blockIdx.x, mh = blockIdx.y;
  const int b = bh >> 3, h = bh & 7, g = h >> 1;
  const int bg = b * 4 + g;
  const int tid = threadIdx.x;
  const int lane = tid & 63, wvi = tid >> 6;
  const int lr = lane & 15, lg = lane >> 4;

  // ---- stage (once per block): rpe-zero, pos, K, V ----
  for (int i = tid; i < 21 * 132; i += 256) rpeL[i] = 0.f;
  posL[tid] = pos[(size_t)bg * 256 + tid];
  const short* kp = k_t + (size_t)b * 128 * 640 + h * 80;
  for (int idx = tid; idx < 1280; idx += 256) {      // K: 128 rows x 10 s8v
    int row = idx / 10, cb = idx - row * 10;
    *(s8v*)&kT[row * 104 + cb * 8] = *(const s8v*)&kp[(size_t)row * 640 + cb * 8];
  }
  for (int idx = tid; idx < 384; idx += 256) {       // zero pad cols 80..103
    int row = idx / 3, cb = idx - row * 3;
    *(s8v*)&kT[row * 104 + 80 + cb * 8] = (s8v)(short)0;
  }
  const short* vp = v_ + ((size_t)b * 640 + h * 80) * 128;
  for (int idx = tid; idx < 1280; idx += 256) {      // V: 80 rows x 16 s8v
    int row = idx >> 4, cb = idx & 15;
    *(s8v*)&vT[row * 136 + cb * 8] = *(const s8v*)&vp[(size_t)row * 128 + cb * 8];
  }
  __syncthreads();
  for (int i = tid; i < 15 * 127; i += 256) {        // rpe interior fill
    int r = i / 127, c = i - r * 127;
    rpeL[(r + 3) * 132 + (c + 3)] = rpe[(size_t)h * (15 * 127) + i];
  }
  __syncthreads();

  // n-dependent bias terms (m-independent): hoisted out of the m-tile loop
  float Pyn[8], Pxn[8];
#pragma unroll
  for (int j = 0; j < 8; ++j) {
    int n_l = j * 16 + lr;
    float py = posL[n_l * 2], px = posL[n_l * 2 + 1];
    Pyn[j] = 10.0f - py * 3.75f;
    Pxn[j] = 66.0f - px * 31.75f;
  }
  const float scale = 0.11180339887498949f;  // 80^-0.5

  const short* qbase = q_t + ((size_t)b * 512 + mh * 256 + wvi * 16) * 640 + h * 80;
  short* aobase = ao_t + ((size_t)b * 512 + mh * 256 + wvi * 16) * 640 + h * 80;

  for (int mt = 0; mt < 4; ++mt) {
    const int m0 = mh * 256 + mt * 64;
    const short* qp = qbase + (size_t)mt * 64 * 640;

    // ---- QK^T: wave-private 16 m-rows x 128 n; Q global, K LDS ----
    f4v acc[8];
#pragma unroll
    for (int j = 0; j < 8; ++j) acc[j] = (f4v)0.0f;
#pragma unroll
    for (int ks = 0; ks < 3; ++ks) {
      const int ch = (ks * 4 + lg) * 8;
      s8v av = (ch < 80) ? *(const s8v*)&qp[(size_t)lr * 640 + ch] : (s8v)(short)0;
#pragma unroll
      for (int j = 0; j < 8; ++j) {
        s8v bv = *(const s8v*)&kT[(j * 16 + lr) * 104 + ch];
        acc[j] = mfma16(av, bv, acc[j]);
      }
    }

    // ---- bias (affine + padded table) + in-wave softmax ----
    float Gy[4], Gx[4];
#pragma unroll
    for (int r = 0; r < 4; ++r) {
      int m_g = m0 + wvi * 16 + lg * 4 + r;
      float qgy = (float)(m_g >> 6) * 0.25f + (0.125f - 1.f);
      float qgx = (float)(m_g & 63) * 0.03125f + (0.015625f - 1.f);
      Gy[r] = qgy * 3.75f;
      Gx[r] = qgx * 31.75f;
    }
    float mx[4] = {-1e30f, -1e30f, -1e30f, -1e30f};
#pragma unroll
    for (int j = 0; j < 8; ++j)
#pragma unroll
      for (int r = 0; r < 4; ++r) {
        float gy = Gy[r] + Pyn[j], gx = Gx[r] + Pxn[j];
        float fy = floorf(gy), fx = floorf(gx);
        int iy = (int)fy, ix = (int)fx;
        float wy = gy - fy, wx = gx - fx;
        const float* t = &rpeL[iy * 132 + ix];
        float t00 = t[0], t01 = t[1], t10 = t[132], t11 = t[133];
        float top = fmaf(wx, t01 - t00, t00);
        float bot = fmaf(wx, t11 - t10, t10);
        float bias = fmaf(wy, bot - top, top);
        float sv = fmaf(acc[j][r], scale, bias);
        acc[j][r] = sv;
        mx[r] = fmaxf(mx[r], sv);
      }
#pragma unroll
    for (int r = 0; r < 4; ++r) {
#pragma unroll
      for (int o = 8; o; o >>= 1) mx[r] = fmaxf(mx[r], __shfl_xor(mx[r], o));
    }
    float sm[4] = {0.f, 0.f, 0.f, 0.f};
#pragma unroll
    for (int j = 0; j < 8; ++j)
#pragma unroll
      for (int r = 0; r < 4; ++r) {
        float e = __expf(acc[j][r] - mx[r]);
        acc[j][r] = e;
        sm[r] += e;
      }
#pragma unroll
    for (int r = 0; r < 4; ++r) {
#pragma unroll
      for (int o = 8; o; o >>= 1) sm[r] += __shfl_xor(sm[r], o);
      sm[r] = 1.f / sm[r];
    }
    // write P into this wave's pT quarter (same-wave RAW -> no barrier)
#pragma unroll
    for (int j = 0; j < 8; ++j)
#pragma unroll
      for (int r = 0; r < 4; ++r)
        pT[(wvi * 16 + lg * 4 + r) * 136 + j * 16 + lr] = f2b(acc[j][r] * sm[r]);

    // ---- PV: P + V from LDS ----
    f4v pacc[5];
#pragma unroll
    for (int t = 0; t < 5; ++t) pacc[t] = (f4v)0.0f;
#pragma unroll
    for (int ks = 0; ks < 4; ++ks) {
      s8v pa = *(const s8v*)&pT[(wvi * 16 + lr) * 136 + ks * 32 + lg * 8];
#pragma unroll
      for (int ct = 0; ct < 5; ++ct) {
        s8v vb = *(const s8v*)&vT[(ct * 16 + lr) * 136 + ks * 32 + lg * 8];
        pacc[ct] = mfma16(pa, vb, pacc[ct]);
      }
    }
    short* aop = aobase + (size_t)mt * 64 * 640;
#pragma unroll
    for (int ct = 0; ct < 5; ++ct)
#pragma unroll
      for (int r = 0; r < 4; ++r)
        aop[(size_t)(lg * 4 + r) * 640 + ct * 16 + lr] = f2b(pacc[ct][r]);
  }
}

// =============================== launcher ===============================
extern "C" void kernel_launch(void* const* d_in, const int* in_sizes, int n_in,
                              void* d_out, int out_size, void* d_ws, size_t ws_size,
                              hipStream_t stream) {
  (void)in_sizes; (void)n_in; (void)out_size; (void)ws_size;
  const float* x   = (const float*)d_in[0];
  const float* y   = (const float*)d_in[1];
  const float* w1  = (const float*)d_in[2];
  const float* b1  = (const float*)d_in[3];
  const float* lng = (const float*)d_in[4];
  const float* lnb = (const float*)d_in[5];
  const float* w2  = (const float*)d_in[6];
  const float* qw  = (const float*)d_in[7];
  const float* qb  = (const float*)d_in[8];
  const float* kw  = (const float*)d_in[9];
  const float* kb  = (const float*)d_in[10];
  const float* vw  = (const float*)d_in[11];
  const float* vb  = (const float*)d_in[12];
  const float* ow  = (const float*)d_in[13];
  const float* ob  = (const float*)d_in[14];
  const float* rpe = (const float*)d_in[15];
  float* out = (float*)d_out;
  float* pos_out = out + 10485760;
  float* ref_out = out + 10518528;

  char* base = (char*)d_ws;
  size_t off = 0;
  auto take = [&](size_t bytes) {
    char* pch = base + off;
    off = (off + bytes + 255) & ~(size_t)255;
    return pch;
  };
  float* pos   = (float*)take(131072);        // [128][128][2] f32
  short* x_t   = (short*)take(20971520);      // [32][512][640] bf16
  short* y_t   = (short*)take(20971520);      // [32][512][640] bf16
  short* q_t   = (short*)take(20971520);      // [32][512][640] bf16
  short* qw_bf = (short*)take(819200);
  short* kw_bf = (short*)take(819200);
  short* vw_bf = (short*)take(819200);
  short* ow_bf = (short*)take(819200);
  short* xs_bf = (short*)take(5242880);       // [32][128][640] bf16
  short* k_t   = (short*)take(5242880);       // [32][128][640] bf16
  short* v_bf  = (short*)take(5242880);       // [32][640][128] bf16
  char*  regB  = take(20971520);              // co (f32 [128][128][320]) then ao_t
  float* co    = (float*)regB;
  short* ao_t  = (short*)regB;                // [32][512][640] bf16

  // transposes + weight converts
  transpose_k<<<dim3(20, 16, 32), dim3(32, 8), 0, stream>>>(x, x_t);
  transpose_k<<<dim3(20, 16, 32), dim3(32, 8), 0, stream>>>(y, y_t);
  cvt_k<<<1600, 256, 0, stream>>>(qw, qw_bf, 409600);
  cvt_k<<<1600, 256, 0, stream>>>(kw, kw_bf, 409600);
  cvt_k<<<1600, 256, 0, stream>>>(vw, vw_bf, 409600);
  cvt_k<<<1600, 256, 0, stream>>>(ow, ow_bf, 409600);

  // offset network
  conv_off_k<<<dim3(40, 128), 256, 0, stream>>>(x, y, w1, b1, co);
  ln_proj_k<<<dim3(32, 128), 256, 0, stream>>>(co, lng, lnb, w2, pos, pos_out, ref_out);

  // deformable sampling
  sample_k<<<dim3(16, 128), 256, 0, stream>>>(x_t, pos, xs_bf);

  // projections (128^2-tile global_load_lds GEMMs; all operands [row][K])
  gemm128_k<true,  false><<<dim3(4, 5, 32), 256, 0, stream>>>(y_t, 512LL * 640, qw_bf, 0LL, qb, q_t, 512, 640, 640);
  gemm128_k<true,  false><<<dim3(1, 5, 32), 256, 0, stream>>>(xs_bf, 128LL * 640, kw_bf, 0LL, kb, k_t, 128, 640, 640);
  gemm128_k<false, false><<<dim3(5, 1, 32), 256, 0, stream>>>(vw_bf, 0LL, xs_bf, 128LL * 640, vb, v_bf, 640, 640, 128);

  // fused attention (QK^T + bias + softmax + PV); 512 blocks, 4 m-tiles each
  qkpv_k<<<dim3(256, 2), 256, 0, stream>>>(q_t, k_t, v_bf, pos, rpe, ao_t);

  // output projection (f32 out)
  gemm128_k<false, true><<<dim3(5, 4, 32), 256, 0, stream>>>(ow_bf, 0LL, ao_t, 512LL * 640, ob, out, 640, 640, 512);
}

// Round 11
// 220.822 us; speedup vs baseline: 1.1780x; 1.0410x over previous
//
#include <hip/hip_runtime.h>

#define DI static __device__ __forceinline__

typedef __attribute__((ext_vector_type(8))) short s8v;
typedef __attribute__((ext_vector_type(4))) float f4v;

DI short f2b(float x) {
  unsigned u = __builtin_bit_cast(unsigned, x);
  u = (u + 0x7fffu + ((u >> 16) & 1u)) >> 16;
  return (short)u;
}
DI float b2f(short s) {
  unsigned u = ((unsigned)(unsigned short)s) << 16;
  return __builtin_bit_cast(float, u);
}
DI f4v mfma16(s8v a, s8v b, f4v c) {
  return __builtin_amdgcn_mfma_f32_16x16x32_bf16(a, b, c, 0, 0, 0);
}
DI void gload16(const short* g, short* l) {
  __builtin_amdgcn_global_load_lds(
      (const __attribute__((address_space(1))) unsigned*)g,
      (__attribute__((address_space(3))) unsigned*)l, 16, 0, 0);
}

// ---------------- f32 -> bf16 convert ----------------
__global__ __launch_bounds__(256) void cvt_k(const float* __restrict__ src,
                                             short* __restrict__ dst, int n) {
  int i = blockIdx.x * 256 + threadIdx.x;
  if (i < n) dst[i] = f2b(src[i]);
}

// ---------------- grouped 9x9 stride-2 conv (offset net part 1) ----------------
// LDS: 8 data rows per channel + ONE shared zero row (no pad rows) -> 21.8 kB,
// ~7 blocks/CU. Out-of-range taps select the zero row via address cndmask.
__global__ __launch_bounds__(256) void conv_off_k(
    const float* __restrict__ x, const float* __restrict__ y,
    const float* __restrict__ w1, const float* __restrict__ b1,
    float* __restrict__ co)
{
  __shared__ float si[8 * 8 * 84 + 84];   // 21.8 kB; zero row at offset 5376
  const int cc = blockIdx.x;        // channel chunk (8 ch)
  const int n  = blockIdx.y;        // b*4+g
  const int b = n >> 2, g = n & 3;
  const int c0 = cc * 8;
  const float* src = (g < 2 ? x : y) + ((size_t)b * 640 + (g & 1) * 320 + c0) * 512;
  const int tid = threadIdx.x;
  float* const zb = &si[8 * 8 * 84];

  // halo zeros: per (ch,row) parity-idx {0,1,34,35} in both halves (disjoint from data fill)
  for (int i = tid; i < 512; i += 256) {
    int chrow = i >> 3, t = i & 7;          // t: par(1b) x idx4(2b)... decode below
    int par = t & 1, which = t >> 1;        // which 0..3 -> idx {0,1,34,35}
    int idx = (which < 2) ? which : 32 + which;
    si[chrow * 84 + par * 42 + idx] = 0.f;
  }
  for (int i = tid; i < 84; i += 256) zb[i] = 0.f;
  // data fill: pc = col+4 in 4..67 -> par=pc&1, idx=pc>>1 (2..33)
  for (int i = tid; i < 8 * 512; i += 256) {
    int ch = i >> 9, idx = i & 511;
    int r = idx >> 6, c = idx & 63;
    int pc = c + 4;
    si[(ch * 8 + r) * 84 + (pc & 1) * 42 + (pc >> 1)] = src[(size_t)ch * 512 + idx];
  }
  __syncthreads();

  const int lane = tid & 63, wvi = tid >> 6;
  const int cl = lane & 15, rg = lane >> 4;
  const int ocs = __builtin_amdgcn_readfirstlane(c0 + 2 * wvi);
  const float* wbase = w1 + (size_t)ocs * 162;
  float a00 = 0.f, a01 = 0.f, a10 = 0.f, a11 = 0.f;  // [oc][col0/col1]
#pragma unroll
  for (int ic = 0; ic < 2; ++ic) {
    const float* chb = &si[(2 * wvi + ic) * 8 * 84];
#pragma unroll
    for (int kh = 0; kh < 9; ++kh) {
      const int row = 2 * rg + kh - 4;                // data row, valid [0,8)
      const float* rp = ((unsigned)row < 8u) ? (chb + row * 84) : zb;
      float ev[6], ov[5];
#pragma unroll
      for (int t = 0; t < 6; ++t) ev[t] = rp[2 * cl + t];
#pragma unroll
      for (int t = 0; t < 5; ++t) ov[t] = rp[42 + 2 * cl + t];
      const float* wv0 = wbase + ic * 81 + kh * 9;
      const float* wv1 = wv0 + 162;
#pragma unroll
      for (int kw = 0; kw < 9; ++kw) {
        float w0 = wv0[kw], w1v = wv1[kw];
        int j = kw >> 1;
        float v0 = (kw & 1) ? ov[j] : ev[j];
        float v1 = (kw & 1) ? ov[j + 1] : ev[j + 1];
        a00 = fmaf(v0, w0, a00);
        a01 = fmaf(v1, w0, a01);
        a10 = fmaf(v0, w1v, a10);
        a11 = fmaf(v1, w1v, a11);
      }
    }
  }
  const float bv0 = b1[ocs], bv1 = b1[ocs + 1];
  const int s0 = rg * 32 + 2 * cl;
  float2 vA = {a00 + bv0, a10 + bv1};
  float2 vB = {a01 + bv0, a11 + bv1};
  *(float2*)&co[((size_t)n * 128 + s0) * 320 + ocs] = vA;
  *(float2*)&co[((size_t)n * 128 + s0 + 1) * 320 + ocs] = vB;
}

// ---------------- LN + GELU + proj + tanh -> pos (offset net part 2) ----------------
__global__ __launch_bounds__(256) void ln_proj_k(
    const float* __restrict__ co, const float* __restrict__ lng,
    const float* __restrict__ lnb, const float* __restrict__ w2,
    float* __restrict__ pos, float* __restrict__ pos_out, float* __restrict__ ref_out)
{
  const int n = blockIdx.y;
  const int wvi = threadIdx.x >> 6, lane = threadIdx.x & 63;
  const int s = blockIdx.x * 4 + wvi;
  const float* cp = co + ((size_t)n * 128 + s) * 320;
  float v[5], gw[5], gb[5], p0[5], p1[5];
#pragma unroll
  for (int t = 0; t < 5; ++t) {
    int ch = lane + 64 * t;
    v[t] = cp[ch]; gw[t] = lng[ch]; gb[t] = lnb[ch];
    p0[t] = w2[ch]; p1[t] = w2[320 + ch];
  }
  float s1 = 0.f, s2 = 0.f;
#pragma unroll
  for (int t = 0; t < 5; ++t) { s1 += v[t]; s2 += v[t] * v[t]; }
#pragma unroll
  for (int o = 32; o; o >>= 1) { s1 += __shfl_xor(s1, o); s2 += __shfl_xor(s2, o); }
  float mu = s1 * (1.f / 320.f);
  float var = s2 * (1.f / 320.f) - mu * mu;
  float rstd = rsqrtf(var + 1e-5f);
  float d0 = 0.f, d1 = 0.f;
#pragma unroll
  for (int t = 0; t < 5; ++t) {
    float xn = (v[t] - mu) * rstd * gw[t] + gb[t];
    float ge = 0.5f * xn * (1.f + erff(xn * 0.70710678118654752f));
    d0 = fmaf(ge, p0[t], d0);
    d1 = fmaf(ge, p1[t], d1);
  }
#pragma unroll
  for (int o = 32; o; o >>= 1) { d0 += __shfl_xor(d0, o); d1 += __shfl_xor(d1, o); }
  if (lane == 0) {
    float oy = tanhf(d0) * 0.5f;
    float ox = tanhf(d1) * 0.0625f;
    int hk = s >> 5, wk = s & 31;
    float ry = ((float)hk + 0.5f) * 0.5f - 1.f;
    float rx = ((float)wk + 0.5f) * 0.0625f - 1.f;
    float py = oy + ry, px = ox + rx;
    size_t o2 = ((size_t)n * 128 + s) * 2;
    pos[o2] = py;     pos[o2 + 1] = px;
    pos_out[o2] = py; pos_out[o2 + 1] = px;
    ref_out[o2] = ry; ref_out[o2 + 1] = rx;
  }
}

// ---------------- transpose [b][c][hw] f32 -> [b][hw][c] bf16 ----------------
__global__ __launch_bounds__(256) void transpose_k(const float* __restrict__ x,
                                                   short* __restrict__ xt) {
  __shared__ float tile[32][33];
  const int ct = blockIdx.x, st = blockIdx.y, b = blockIdx.z;
  const int tx = threadIdx.x, ty = threadIdx.y;
  const float* src = x + ((size_t)b * 640 + ct * 32) * 512 + st * 32;
#pragma unroll
  for (int k2 = 0; k2 < 4; ++k2)
    tile[ty + 8 * k2][tx] = src[(size_t)(ty + 8 * k2) * 512 + tx];
  __syncthreads();
  short* dst = xt + ((size_t)b * 512 + st * 32) * 640 + ct * 32;
#pragma unroll
  for (int k2 = 0; k2 < 4; ++k2)
    dst[(size_t)(ty + 8 * k2) * 640 + tx] = f2b(tile[tx][ty + 8 * k2]);
}

// ---------------- bilinear sampler: xs[b][n=128][c=640] bf16 ----------------
__global__ __launch_bounds__(256) void sample_k(const short* __restrict__ xt,
                                                const float* __restrict__ pos,
                                                short* __restrict__ xs) {
  const int sc = blockIdx.x, bg = blockIdx.y;
  const int b = bg >> 2, g = bg & 3;
  const int t = threadIdx.x;
  const int s = sc * 8 + (t >> 5);
  const int ci = t & 31;
  size_t p2 = ((size_t)bg * 128 + s) * 2;
  float py = pos[p2], px = pos[p2 + 1];
  float gx = (px + 1.f) * 32.f - 0.5f;
  float gy = (py + 1.f) * 4.f - 0.5f;
  float fx = floorf(gx), fy = floorf(gy);
  int x0 = (int)fx, y0 = (int)fy;
  float wx1 = gx - fx, wx0 = 1.f - wx1;
  float wy1 = gy - fy, wy0 = 1.f - wy1;
  int xx[2] = {x0, x0 + 1}, yy[2] = {y0, y0 + 1};
  float wxs[2] = {wx0, wx1}, wys[2] = {wy0, wy1};
  const short* basep = xt + (size_t)b * 512 * 640 + (size_t)g * 160;
  short* outp = xs + ((size_t)(b * 128 + s)) * 640 + g * 160;
#pragma unroll
  for (int kk = 0; kk < 5; ++kk) {
    int c = kk * 32 + ci;
    float acc = 0.f;
#pragma unroll
    for (int ty = 0; ty < 2; ++ty) {
      int yv = yy[ty];
      bool vy = (yv >= 0) & (yv < 8);
      int yc = min(max(yv, 0), 7);
#pragma unroll
      for (int tx = 0; tx < 2; ++tx) {
        int xv = xx[tx];
        bool vv = vy & (xv >= 0) & (xv < 64);
        int xc = min(max(xv, 0), 63);
        float val = b2f(basep[((size_t)yc * 64 + xc) * 640 + c]);
        acc += wys[ty] * wxs[tx] * (vv ? val : 0.f);
      }
    }
    outp[c] = f2b(acc);
  }
}

// ---------------- 128x128-tile MFMA GEMM with global_load_lds (m97 structure) ----
template <bool BIASN, bool OUTF32>
__global__ __launch_bounds__(256) void gemm128_k(
    const short* __restrict__ W, long long wStride,
    const short* __restrict__ X, long long xStride,
    const float* __restrict__ bias, void* __restrict__ Out,
    int M, int K, int N)
{
  __shared__ short wa[128 * 32];
  __shared__ short xb[128 * 32];
  const int m0 = blockIdx.x * 128, n0 = blockIdx.y * 128;
  const int bz = blockIdx.z;
  const short* Wp = W + (size_t)bz * wStride + (size_t)m0 * K;
  const short* Xp = X + (size_t)bz * xStride + (size_t)n0 * K;
  const int tid = threadIdx.x;
  const int lane = tid & 63;
  const int wvi = __builtin_amdgcn_readfirstlane(tid >> 6);
  const int wr = wvi >> 1, wc = wvi & 1, lr = lane & 15, lg = lane >> 4;

  const int r0 = (wvi * 16) + (lane >> 2);
  const int cb = (lane & 3) * 8;
  const short* wg0 = Wp + (size_t)r0 * K + cb;
  const short* wg1 = Wp + (size_t)(r0 + 64) * K + cb;
  const short* xg0 = Xp + (size_t)r0 * K + cb;
  const short* xg1 = Xp + (size_t)(r0 + 64) * K + cb;
  short* la0 = &wa[wvi * 512];
  short* la1 = &wa[(4 + wvi) * 512];
  short* lb0 = &xb[wvi * 512];
  short* lb1 = &xb[(4 + wvi) * 512];

  f4v acc[4][4];
#pragma unroll
  for (int i = 0; i < 4; ++i)
#pragma unroll
    for (int j = 0; j < 4; ++j) acc[i][j] = (f4v)0.0f;

  const int nk = K >> 5;
  for (int ks = 0; ks < nk; ++ks) {
    __syncthreads();
    const int ko = ks * 32;
    gload16(wg0 + ko, la0);
    gload16(wg1 + ko, la1);
    gload16(xg0 + ko, lb0);
    gload16(xg1 + ko, lb1);
    __syncthreads();
    s8v av[4], bv[4];
#pragma unroll
    for (int i = 0; i < 4; ++i)
      av[i] = *(const s8v*)&wa[(wr * 64 + i * 16 + lr) * 32 + lg * 8];
#pragma unroll
    for (int j = 0; j < 4; ++j)
      bv[j] = *(const s8v*)&xb[(wc * 64 + j * 16 + lr) * 32 + lg * 8];
#pragma unroll
    for (int i = 0; i < 4; ++i)
#pragma unroll
      for (int j = 0; j < 4; ++j)
        acc[i][j] = mfma16(av[i], bv[j], acc[i][j]);
  }

#pragma unroll
  for (int i = 0; i < 4; ++i)
#pragma unroll
    for (int j = 0; j < 4; ++j)
#pragma unroll
      for (int r = 0; r < 4; ++r) {
        int m_g = m0 + wr * 64 + i * 16 + lg * 4 + r;
        int n_g = n0 + wc * 64 + j * 16 + lr;
        float val = acc[i][j][r] + (BIASN ? bias[n_g] : bias[m_g]);
        size_t oidx = (size_t)bz * M * N + (size_t)m_g * N + n_g;
        if (OUTF32) ((float*)Out)[oidx] = val;
        else        ((short*)Out)[oidx] = f2b(val);
      }
}

// ---------------- fused QK^T + RPE bias + softmax + PV -> ao_t (bf16) -------------
__global__ __launch_bounds__(256) void qkpv_k(
    const short* __restrict__ q_t, const short* __restrict__ k_t,
    const short* __restrict__ v_, const float* __restrict__ pos,
    const float* __restrict__ rpe, short* __restrict__ ao_t)
{
  __shared__ short kT[128 * 104];     // 26.6 kB, stride 104 (2-way-free)
  __shared__ short vT[80 * 136];      // 21.8 kB, stride 136
  __shared__ short pT[64 * 136];      // 17.4 kB (wave-private quarters)
  __shared__ float rpeL[21 * 132];    // 11.1 kB, zero-padded ring of 3
  __shared__ float posL[256];
  const int bh = blockIdx.x, mh = blockIdx.y;
  const int b = bh >> 3, h = bh & 7, g = h >> 1;
  const int bg = b * 4 + g;
  const int tid = threadIdx.x;
  const int lane = tid & 63, wvi = tid >> 6;
  const int lr = lane & 15, lg = lane >> 4;

  // ---- stage (once per block): rpe-zero, pos, K, V ----
  for (int i = tid; i < 21 * 132; i += 256) rpeL[i] = 0.f;
  posL[tid] = pos[(size_t)bg * 256 + tid];
  const short* kp = k_t + (size_t)b * 128 * 640 + h * 80;
  for (int idx = tid; idx < 1280; idx += 256) {      // K: 128 rows x 10 s8v
    int row = idx / 10, cb = idx - row * 10;
    *(s8v*)&kT[row * 104 + cb * 8] = *(const s8v*)&kp[(size_t)row * 640 + cb * 8];
  }
  for (int idx = tid; idx < 384; idx += 256) {       // zero pad cols 80..103
    int row = idx / 3, cb = idx - row * 3;
    *(s8v*)&kT[row * 104 + 80 + cb * 8] = (s8v)(short)0;
  }
  const short* vp = v_ + ((size_t)b * 640 + h * 80) * 128;
  for (int idx = tid; idx < 1280; idx += 256) {      // V: 80 rows x 16 s8v
    int row = idx >> 4, cb = idx & 15;
    *(s8v*)&vT[row * 136 + cb * 8] = *(const s8v*)&vp[(size_t)row * 128 + cb * 8];
  }
  __syncthreads();
  for (int i = tid; i < 15 * 127; i += 256) {        // rpe interior fill
    int r = i / 127, c = i - r * 127;
    rpeL[(r + 3) * 132 + (c + 3)] = rpe[(size_t)h * (15 * 127) + i];
  }
  __syncthreads();

  // n-dependent bias terms (m-independent): hoisted out of the m-tile loop
  float Pyn[8], Pxn[8];
#pragma unroll
  for (int j = 0; j < 8; ++j) {
    int n_l = j * 16 + lr;
    float py = posL[n_l * 2], px = posL[n_l * 2 + 1];
    Pyn[j] = 10.0f - py * 3.75f;
    Pxn[j] = 66.0f - px * 31.75f;
  }
  const float scale = 0.11180339887498949f;  // 80^-0.5

  const short* qbase = q_t + ((size_t)b * 512 + mh * 256 + wvi * 16) * 640 + h * 80;
  short* aobase = ao_t + ((size_t)b * 512 + mh * 256 + wvi * 16) * 640 + h * 80;

  for (int mt = 0; mt < 4; ++mt) {
    const int m0 = mh * 256 + mt * 64;
    const short* qp = qbase + (size_t)mt * 64 * 640;

    // ---- QK^T: wave-private 16 m-rows x 128 n; Q global, K LDS ----
    f4v acc[8];
#pragma unroll
    for (int j = 0; j < 8; ++j) acc[j] = (f4v)0.0f;
#pragma unroll
    for (int ks = 0; ks < 3; ++ks) {
      const int ch = (ks * 4 + lg) * 8;
      s8v av = (ch < 80) ? *(const s8v*)&qp[(size_t)lr * 640 + ch] : (s8v)(short)0;
#pragma unroll
      for (int j = 0; j < 8; ++j) {
        s8v bv = *(const s8v*)&kT[(j * 16 + lr) * 104 + ch];
        acc[j] = mfma16(av, bv, acc[j]);
      }
    }

    // ---- bias (affine + padded table) + in-wave softmax ----
    float Gy[4], Gx[4];
#pragma unroll
    for (int r = 0; r < 4; ++r) {
      int m_g = m0 + wvi * 16 + lg * 4 + r;
      float qgy = (float)(m_g >> 6) * 0.25f + (0.125f - 1.f);
      float qgx = (float)(m_g & 63) * 0.03125f + (0.015625f - 1.f);
      Gy[r] = qgy * 3.75f;
      Gx[r] = qgx * 31.75f;
    }
    float mx[4] = {-1e30f, -1e30f, -1e30f, -1e30f};
#pragma unroll
    for (int j = 0; j < 8; ++j)
#pragma unroll
      for (int r = 0; r < 4; ++r) {
        float gy = Gy[r] + Pyn[j], gx = Gx[r] + Pxn[j];
        float fy = floorf(gy), fx = floorf(gx);
        int iy = (int)fy, ix = (int)fx;
        float wy = gy - fy, wx = gx - fx;
        const float* t = &rpeL[iy * 132 + ix];
        float t00 = t[0], t01 = t[1], t10 = t[132], t11 = t[133];
        float top = fmaf(wx, t01 - t00, t00);
        float bot = fmaf(wx, t11 - t10, t10);
        float bias = fmaf(wy, bot - top, top);
        float sv = fmaf(acc[j][r], scale, bias);
        acc[j][r] = sv;
        mx[r] = fmaxf(mx[r], sv);
      }
#pragma unroll
    for (int r = 0; r < 4; ++r) {
#pragma unroll
      for (int o = 8; o; o >>= 1) mx[r] = fmaxf(mx[r], __shfl_xor(mx[r], o));
    }
    float sm[4] = {0.f, 0.f, 0.f, 0.f};
#pragma unroll
    for (int j = 0; j < 8; ++j)
#pragma unroll
      for (int r = 0; r < 4; ++r) {
        float e = __expf(acc[j][r] - mx[r]);
        acc[j][r] = e;
        sm[r] += e;
      }
#pragma unroll
    for (int r = 0; r < 4; ++r) {
#pragma unroll
      for (int o = 8; o; o >>= 1) sm[r] += __shfl_xor(sm[r], o);
      sm[r] = 1.f / sm[r];
    }
    // write P into this wave's pT quarter (same-wave RAW -> no barrier)
#pragma unroll
    for (int j = 0; j < 8; ++j)
#pragma unroll
      for (int r = 0; r < 4; ++r)
        pT[(wvi * 16 + lg * 4 + r) * 136 + j * 16 + lr] = f2b(acc[j][r] * sm[r]);

    // ---- PV: P + V from LDS ----
    f4v pacc[5];
#pragma unroll
    for (int t = 0; t < 5; ++t) pacc[t] = (f4v)0.0f;
#pragma unroll
    for (int ks = 0; ks < 4; ++ks) {
      s8v pa = *(const s8v*)&pT[(wvi * 16 + lr) * 136 + ks * 32 + lg * 8];
#pragma unroll
      for (int ct = 0; ct < 5; ++ct) {
        s8v vb = *(const s8v*)&vT[(ct * 16 + lr) * 136 + ks * 32 + lg * 8];
        pacc[ct] = mfma16(pa, vb, pacc[ct]);
      }
    }
    short* aop = aobase + (size_t)mt * 64 * 640;
#pragma unroll
    for (int ct = 0; ct < 5; ++ct)
#pragma unroll
      for (int r = 0; r < 4; ++r)
        aop[(size_t)(lg * 4 + r) * 640 + ct * 16 + lr] = f2b(pacc[ct][r]);
  }
}

// =============================== launcher ===============================
extern "C" void kernel_launch(void* const* d_in, const int* in_sizes, int n_in,
                              void* d_out, int out_size, void* d_ws, size_t ws_size,
                              hipStream_t stream) {
  (void)in_sizes; (void)n_in; (void)out_size; (void)ws_size;
  const float* x   = (const float*)d_in[0];
  const float* y   = (const float*)d_in[1];
  const float* w1  = (const float*)d_in[2];
  const float* b1  = (const float*)d_in[3];
  const float* lng = (const float*)d_in[4];
  const float* lnb = (const float*)d_in[5];
  const float* w2  = (const float*)d_in[6];
  const float* qw  = (const float*)d_in[7];
  const float* qb  = (const float*)d_in[8];
  const float* kw  = (const float*)d_in[9];
  const float* kb  = (const float*)d_in[10];
  const float* vw  = (const float*)d_in[11];
  const float* vb  = (const float*)d_in[12];
  const float* ow  = (const float*)d_in[13];
  const float* ob  = (const float*)d_in[14];
  const float* rpe = (const float*)d_in[15];
  float* out = (float*)d_out;
  float* pos_out = out + 10485760;
  float* ref_out = out + 10518528;

  char* base = (char*)d_ws;
  size_t off = 0;
  auto take = [&](size_t bytes) {
    char* pch = base + off;
    off = (off + bytes + 255) & ~(size_t)255;
    return pch;
  };
  float* pos   = (float*)take(131072);        // [128][128][2] f32
  short* x_t   = (short*)take(20971520);      // [32][512][640] bf16
  short* y_t   = (short*)take(20971520);      // [32][512][640] bf16
  short* q_t   = (short*)take(20971520);      // [32][512][640] bf16
  short* qw_bf = (short*)take(819200);
  short* kw_bf = (short*)take(819200);
  short* vw_bf = (short*)take(819200);
  short* ow_bf = (short*)take(819200);
  short* xs_bf = (short*)take(5242880);       // [32][128][640] bf16
  short* k_t   = (short*)take(5242880);       // [32][128][640] bf16
  short* v_bf  = (short*)take(5242880);       // [32][640][128] bf16
  char*  regB  = take(20971520);              // co (f32 [128][128][320]) then ao_t
  float* co    = (float*)regB;
  short* ao_t  = (short*)regB;                // [32][512][640] bf16

  // transposes + weight converts
  transpose_k<<<dim3(20, 16, 32), dim3(32, 8), 0, stream>>>(x, x_t);
  transpose_k<<<dim3(20, 16, 32), dim3(32, 8), 0, stream>>>(y, y_t);
  cvt_k<<<1600, 256, 0, stream>>>(qw, qw_bf, 409600);
  cvt_k<<<1600, 256, 0, stream>>>(kw, kw_bf, 409600);
  cvt_k<<<1600, 256, 0, stream>>>(vw, vw_bf, 409600);
  cvt_k<<<1600, 256, 0, stream>>>(ow, ow_bf, 409600);

  // offset network
  conv_off_k<<<dim3(40, 128), 256, 0, stream>>>(x, y, w1, b1, co);
  ln_proj_k<<<dim3(32, 128), 256, 0, stream>>>(co, lng, lnb, w2, pos, pos_out, ref_out);

  // deformable sampling
  sample_k<<<dim3(16, 128), 256, 0, stream>>>(x_t, pos, xs_bf);

  // projections (128^2-tile global_load_lds GEMMs; all operands [row][K])
  gemm128_k<true,  false><<<dim3(4, 5, 32), 256, 0, stream>>>(y_t, 512LL * 640, qw_bf, 0LL, qb, q_t, 512, 640, 640);
  gemm128_k<true,  false><<<dim3(1, 5, 32), 256, 0, stream>>>(xs_bf, 128LL * 640, kw_bf, 0LL, kb, k_t, 128, 640, 640);
  gemm128_k<false, false><<<dim3(5, 1, 32), 256, 0, stream>>>(vw_bf, 0LL, xs_bf, 128LL * 640, vb, v_bf, 640, 640, 128);

  // fused attention (QK^T + bias + softmax + PV); 512 blocks, 4 m-tiles each
  qkpv_k<<<dim3(256, 2), 256, 0, stream>>>(q_t, k_t, v_bf, pos, rpe, ao_t);

  // output projection (f32 out)
  gemm128_k<false, true><<<dim3(5, 4, 32), 256, 0, stream>>>(ow_bf, 0LL, ao_t, 512LL * 640, ob, out, 640, 640, 512);
}

// Round 12
// 217.040 us; speedup vs baseline: 1.1986x; 1.0174x over previous
//
#include <hip/hip_runtime.h>

#define DI static __device__ __forceinline__

typedef __attribute__((ext_vector_type(8))) short s8v;
typedef __attribute__((ext_vector_type(4))) short s4v;
typedef __attribute__((ext_vector_type(4))) float f4v;

DI short f2b(float x) {
  unsigned u = __builtin_bit_cast(unsigned, x);
  u = (u + 0x7fffu + ((u >> 16) & 1u)) >> 16;
  return (short)u;
}
DI float b2f(short s) {
  unsigned u = ((unsigned)(unsigned short)s) << 16;
  return __builtin_bit_cast(float, u);
}
DI f4v mfma16(s8v a, s8v b, f4v c) {
  return __builtin_amdgcn_mfma_f32_16x16x32_bf16(a, b, c, 0, 0, 0);
}
DI void gload16(const short* g, short* l) {
  __builtin_amdgcn_global_load_lds(
      (const __attribute__((address_space(1))) unsigned*)g,
      (__attribute__((address_space(3))) unsigned*)l, 16, 0, 0);
}

// ---------------- batched f32 -> bf16 convert (4 weight matrices) ----------------
__global__ __launch_bounds__(256) void cvtw4_k(
    const float* __restrict__ s0, const float* __restrict__ s1,
    const float* __restrict__ s2, const float* __restrict__ s3,
    short* __restrict__ d0, short* __restrict__ d1,
    short* __restrict__ d2, short* __restrict__ d3) {
  int w = blockIdx.y;
  const float* s = (w == 0) ? s0 : (w == 1) ? s1 : (w == 2) ? s2 : s3;
  short* d = (w == 0) ? d0 : (w == 1) ? d1 : (w == 2) ? d2 : d3;
  int i = blockIdx.x * 256 + threadIdx.x;
  d[i] = f2b(s[i]);
}

// ---------------- grouped 9x9 stride-2 conv (offset net part 1) ----------------
__global__ __launch_bounds__(256) void conv_off_k(
    const float* __restrict__ x, const float* __restrict__ y,
    const float* __restrict__ w1, const float* __restrict__ b1,
    float* __restrict__ co)
{
  __shared__ float si[8 * 8 * 84 + 84];   // 21.8 kB; zero row at offset 5376
  const int cc = blockIdx.x;
  const int n  = blockIdx.y;
  const int b = n >> 2, g = n & 3;
  const int c0 = cc * 8;
  const float* src = (g < 2 ? x : y) + ((size_t)b * 640 + (g & 1) * 320 + c0) * 512;
  const int tid = threadIdx.x;
  float* const zb = &si[8 * 8 * 84];

  for (int i = tid; i < 512; i += 256) {
    int chrow = i >> 3, t = i & 7;
    int par = t & 1, which = t >> 1;
    int idx = (which < 2) ? which : 32 + which;
    si[chrow * 84 + par * 42 + idx] = 0.f;
  }
  for (int i = tid; i < 84; i += 256) zb[i] = 0.f;
  for (int i = tid; i < 8 * 512; i += 256) {
    int ch = i >> 9, idx = i & 511;
    int r = idx >> 6, c = idx & 63;
    int pc = c + 4;
    si[(ch * 8 + r) * 84 + (pc & 1) * 42 + (pc >> 1)] = src[(size_t)ch * 512 + idx];
  }
  __syncthreads();

  const int lane = tid & 63, wvi = tid >> 6;
  const int cl = lane & 15, rg = lane >> 4;
  const int ocs = __builtin_amdgcn_readfirstlane(c0 + 2 * wvi);
  const float* wbase = w1 + (size_t)ocs * 162;
  float a00 = 0.f, a01 = 0.f, a10 = 0.f, a11 = 0.f;
#pragma unroll
  for (int ic = 0; ic < 2; ++ic) {
    const float* chb = &si[(2 * wvi + ic) * 8 * 84];
#pragma unroll
    for (int kh = 0; kh < 9; ++kh) {
      const int row = 2 * rg + kh - 4;
      const float* rp = ((unsigned)row < 8u) ? (chb + row * 84) : zb;
      float ev[6], ov[5];
#pragma unroll
      for (int t = 0; t < 6; ++t) ev[t] = rp[2 * cl + t];
#pragma unroll
      for (int t = 0; t < 5; ++t) ov[t] = rp[42 + 2 * cl + t];
      const float* wv0 = wbase + ic * 81 + kh * 9;
      const float* wv1 = wv0 + 162;
#pragma unroll
      for (int kw = 0; kw < 9; ++kw) {
        float w0 = wv0[kw], w1v = wv1[kw];
        int j = kw >> 1;
        float v0 = (kw & 1) ? ov[j] : ev[j];
        float v1 = (kw & 1) ? ov[j + 1] : ev[j + 1];
        a00 = fmaf(v0, w0, a00);
        a01 = fmaf(v1, w0, a01);
        a10 = fmaf(v0, w1v, a10);
        a11 = fmaf(v1, w1v, a11);
      }
    }
  }
  const float bv0 = b1[ocs], bv1 = b1[ocs + 1];
  const int s0 = rg * 32 + 2 * cl;
  float2 vA = {a00 + bv0, a10 + bv1};
  float2 vB = {a01 + bv0, a11 + bv1};
  *(float2*)&co[((size_t)n * 128 + s0) * 320 + ocs] = vA;
  *(float2*)&co[((size_t)n * 128 + s0 + 1) * 320 + ocs] = vB;
}

// ---------------- LN + GELU + proj + tanh -> pos (offset net part 2) ----------------
__global__ __launch_bounds__(256) void ln_proj_k(
    const float* __restrict__ co, const float* __restrict__ lng,
    const float* __restrict__ lnb, const float* __restrict__ w2,
    float* __restrict__ pos, float* __restrict__ pos_out, float* __restrict__ ref_out)
{
  const int n = blockIdx.y;
  const int wvi = threadIdx.x >> 6, lane = threadIdx.x & 63;
  const int s = blockIdx.x * 4 + wvi;
  const float* cp = co + ((size_t)n * 128 + s) * 320;
  float v[5], gw[5], gb[5], p0[5], p1[5];
#pragma unroll
  for (int t = 0; t < 5; ++t) {
    int ch = lane + 64 * t;
    v[t] = cp[ch]; gw[t] = lng[ch]; gb[t] = lnb[ch];
    p0[t] = w2[ch]; p1[t] = w2[320 + ch];
  }
  float s1 = 0.f, s2 = 0.f;
#pragma unroll
  for (int t = 0; t < 5; ++t) { s1 += v[t]; s2 += v[t] * v[t]; }
#pragma unroll
  for (int o = 32; o; o >>= 1) { s1 += __shfl_xor(s1, o); s2 += __shfl_xor(s2, o); }
  float mu = s1 * (1.f / 320.f);
  float var = s2 * (1.f / 320.f) - mu * mu;
  float rstd = rsqrtf(var + 1e-5f);
  float d0 = 0.f, d1 = 0.f;
#pragma unroll
  for (int t = 0; t < 5; ++t) {
    float xn = (v[t] - mu) * rstd * gw[t] + gb[t];
    float ge = 0.5f * xn * (1.f + erff(xn * 0.70710678118654752f));
    d0 = fmaf(ge, p0[t], d0);
    d1 = fmaf(ge, p1[t], d1);
  }
#pragma unroll
  for (int o = 32; o; o >>= 1) { d0 += __shfl_xor(d0, o); d1 += __shfl_xor(d1, o); }
  if (lane == 0) {
    float oy = tanhf(d0) * 0.5f;
    float ox = tanhf(d1) * 0.0625f;
    int hk = s >> 5, wk = s & 31;
    float ry = ((float)hk + 0.5f) * 0.5f - 1.f;
    float rx = ((float)wk + 0.5f) * 0.0625f - 1.f;
    float py = oy + ry, px = ox + rx;
    size_t o2 = ((size_t)n * 128 + s) * 2;
    pos[o2] = py;     pos[o2 + 1] = px;
    pos_out[o2] = py; pos_out[o2 + 1] = px;
    ref_out[o2] = ry; ref_out[o2 + 1] = rx;
  }
}

// ---------------- transpose both x,y: [b][c][hw] f32 -> [b][hw][c] bf16 ----------------
__global__ __launch_bounds__(256) void transpose_k(
    const float* __restrict__ x, const float* __restrict__ y,
    short* __restrict__ xt, short* __restrict__ yt) {
  __shared__ float tile[32][33];
  const int ct = blockIdx.x, st = blockIdx.y, z = blockIdx.z;
  const int b = z & 31;
  const float* srcm = (z < 32) ? x : y;
  short* dstm = (z < 32) ? xt : yt;
  const int tx = threadIdx.x, ty = threadIdx.y;
  const float* src = srcm + ((size_t)b * 640 + ct * 32) * 512 + st * 32;
#pragma unroll
  for (int k2 = 0; k2 < 4; ++k2)
    tile[ty + 8 * k2][tx] = src[(size_t)(ty + 8 * k2) * 512 + tx];
  __syncthreads();
  short* dst = dstm + ((size_t)b * 512 + st * 32) * 640 + ct * 32;
#pragma unroll
  for (int k2 = 0; k2 < 4; ++k2)
    dst[(size_t)(ty + 8 * k2) * 640 + tx] = f2b(tile[tx][ty + 8 * k2]);
}

// ---------------- bilinear sampler: xs[b][n=128][c=640] bf16 ----------------
__global__ __launch_bounds__(256) void sample_k(const short* __restrict__ xt,
                                                const float* __restrict__ pos,
                                                short* __restrict__ xs) {
  const int sc = blockIdx.x, bg = blockIdx.y;
  const int b = bg >> 2, g = bg & 3;
  const int t = threadIdx.x;
  const int s = sc * 8 + (t >> 5);
  const int ci = t & 31;
  size_t p2 = ((size_t)bg * 128 + s) * 2;
  float py = pos[p2], px = pos[p2 + 1];
  float gx = (px + 1.f) * 32.f - 0.5f;
  float gy = (py + 1.f) * 4.f - 0.5f;
  float fx = floorf(gx), fy = floorf(gy);
  int x0 = (int)fx, y0 = (int)fy;
  float wx1 = gx - fx, wx0 = 1.f - wx1;
  float wy1 = gy - fy, wy0 = 1.f - wy1;
  int xx[2] = {x0, x0 + 1}, yy[2] = {y0, y0 + 1};
  float wxs[2] = {wx0, wx1}, wys[2] = {wy0, wy1};
  const short* basep = xt + (size_t)b * 512 * 640 + (size_t)g * 160;
  short* outp = xs + ((size_t)(b * 128 + s)) * 640 + g * 160;
#pragma unroll
  for (int kk = 0; kk < 5; ++kk) {
    int c = kk * 32 + ci;
    float acc = 0.f;
#pragma unroll
    for (int ty = 0; ty < 2; ++ty) {
      int yv = yy[ty];
      bool vy = (yv >= 0) & (yv < 8);
      int yc = min(max(yv, 0), 7);
#pragma unroll
      for (int tx = 0; tx < 2; ++tx) {
        int xv = xx[tx];
        bool vv = vy & (xv >= 0) & (xv < 64);
        int xc = min(max(xv, 0), 63);
        float val = b2f(basep[((size_t)yc * 64 + xc) * 640 + c]);
        acc += wys[ty] * wxs[tx] * (vv ? val : 0.f);
      }
    }
    outp[c] = f2b(acc);
  }
}

// ---------------- 128x128-tile MFMA GEMM with global_load_lds (m97 structure) ----
template <bool BIASN, bool OUTF32>
__global__ __launch_bounds__(256) void gemm128_k(
    const short* __restrict__ W, long long wStride,
    const short* __restrict__ X, long long xStride,
    const float* __restrict__ bias, void* __restrict__ Out,
    int M, int K, int N)
{
  __shared__ short wa[128 * 32];
  __shared__ short xb[128 * 32];
  const int m0 = blockIdx.x * 128, n0 = blockIdx.y * 128;
  const int bz = blockIdx.z;
  const short* Wp = W + (size_t)bz * wStride + (size_t)m0 * K;
  const short* Xp = X + (size_t)bz * xStride + (size_t)n0 * K;
  const int tid = threadIdx.x;
  const int lane = tid & 63;
  const int wvi = __builtin_amdgcn_readfirstlane(tid >> 6);
  const int wr = wvi >> 1, wc = wvi & 1, lr = lane & 15, lg = lane >> 4;

  const int r0 = (wvi * 16) + (lane >> 2);
  const int cb = (lane & 3) * 8;
  const short* wg0 = Wp + (size_t)r0 * K + cb;
  const short* wg1 = Wp + (size_t)(r0 + 64) * K + cb;
  const short* xg0 = Xp + (size_t)r0 * K + cb;
  const short* xg1 = Xp + (size_t)(r0 + 64) * K + cb;
  short* la0 = &wa[wvi * 512];
  short* la1 = &wa[(4 + wvi) * 512];
  short* lb0 = &xb[wvi * 512];
  short* lb1 = &xb[(4 + wvi) * 512];

  f4v acc[4][4];
#pragma unroll
  for (int i = 0; i < 4; ++i)
#pragma unroll
    for (int j = 0; j < 4; ++j) acc[i][j] = (f4v)0.0f;

  const int nk = K >> 5;
  for (int ks = 0; ks < nk; ++ks) {
    __syncthreads();
    const int ko = ks * 32;
    gload16(wg0 + ko, la0);
    gload16(wg1 + ko, la1);
    gload16(xg0 + ko, lb0);
    gload16(xg1 + ko, lb1);
    __syncthreads();
    s8v av[4], bv[4];
#pragma unroll
    for (int i = 0; i < 4; ++i)
      av[i] = *(const s8v*)&wa[(wr * 64 + i * 16 + lr) * 32 + lg * 8];
#pragma unroll
    for (int j = 0; j < 4; ++j)
      bv[j] = *(const s8v*)&xb[(wc * 64 + j * 16 + lr) * 32 + lg * 8];
#pragma unroll
    for (int i = 0; i < 4; ++i)
#pragma unroll
      for (int j = 0; j < 4; ++j)
        acc[i][j] = mfma16(av[i], bv[j], acc[i][j]);
  }

#pragma unroll
  for (int i = 0; i < 4; ++i)
#pragma unroll
    for (int j = 0; j < 4; ++j)
#pragma unroll
      for (int r = 0; r < 4; ++r) {
        int m_g = m0 + wr * 64 + i * 16 + lg * 4 + r;
        int n_g = n0 + wc * 64 + j * 16 + lr;
        float val = acc[i][j][r] + (BIASN ? bias[n_g] : bias[m_g]);
        size_t oidx = (size_t)bz * M * N + (size_t)m_g * N + n_g;
        if (OUTF32) ((float*)Out)[oidx] = val;
        else        ((short*)Out)[oidx] = f2b(val);
      }
}

// ---------------- fused QK^T + RPE bias + softmax + PV -> ao_t (bf16) -------------
// SWAPPED QK: acc = mfma(K, Q) holds S^T -> each lane owns ONE m-row (m = lr).
// Softmax: 32 in-lane + 2 shuffles. P-write: 8x ds_write_b64 (consecutive n).
// Bias n-terms from LDS tables (pynL/pxnL), m-terms 2 scalars/lane.
__global__ __launch_bounds__(256) void qkpv_k(
    const short* __restrict__ q_t, const short* __restrict__ k_t,
    const short* __restrict__ v_, const float* __restrict__ pos,
    const float* __restrict__ rpe, short* __restrict__ ao_t)
{
  __shared__ short kT[128 * 104];     // 26.6 kB
  __shared__ short vT[80 * 136];      // 21.8 kB
  __shared__ short pT[64 * 136];      // 17.4 kB (wave-private 16-row bands)
  __shared__ float rpeL[21 * 132];    // 11.1 kB zero-padded
  __shared__ float pynL[128], pxnL[128];
  const int bh = blockIdx.x, mh = blockIdx.y;
  const int b = bh >> 3, h = bh & 7, g = h >> 1;
  const int bg = b * 4 + g;
  const int tid = threadIdx.x;
  const int lane = tid & 63, wvi = tid >> 6;
  const int lr = lane & 15, lg = lane >> 4;

  // ---- stage once per block ----
  for (int i = tid; i < 21 * 132; i += 256) rpeL[i] = 0.f;
  if (tid < 128) {
    float py = pos[(size_t)bg * 256 + tid * 2];
    float px = pos[(size_t)bg * 256 + tid * 2 + 1];
    pynL[tid] = 10.0f - py * 3.75f;
    pxnL[tid] = 66.0f - px * 31.75f;
  }
  const short* kp = k_t + (size_t)b * 128 * 640 + h * 80;
  for (int idx = tid; idx < 1280; idx += 256) {
    int row = idx / 10, cb = idx - row * 10;
    *(s8v*)&kT[row * 104 + cb * 8] = *(const s8v*)&kp[(size_t)row * 640 + cb * 8];
  }
  for (int idx = tid; idx < 384; idx += 256) {
    int row = idx / 3, cb = idx - row * 3;
    *(s8v*)&kT[row * 104 + 80 + cb * 8] = (s8v)(short)0;
  }
  const short* vp = v_ + ((size_t)b * 640 + h * 80) * 128;
  for (int idx = tid; idx < 1280; idx += 256) {
    int row = idx >> 4, cb = idx & 15;
    *(s8v*)&vT[row * 136 + cb * 8] = *(const s8v*)&vp[(size_t)row * 128 + cb * 8];
  }
  __syncthreads();
  for (int i = tid; i < 15 * 127; i += 256) {
    int r = i / 127, c = i - r * 127;
    rpeL[(r + 3) * 132 + (c + 3)] = rpe[(size_t)h * (15 * 127) + i];
  }
  __syncthreads();

  const float scale = 0.11180339887498949f;  // 80^-0.5
  const short* qbase = q_t + ((size_t)b * 512 + mh * 256 + wvi * 16) * 640 + h * 80;
  short* aobase = ao_t + ((size_t)b * 512 + mh * 256 + wvi * 16) * 640 + h * 80;

  for (int mt = 0; mt < 4; ++mt) {
    const int m0 = mh * 256 + mt * 64;
    const short* qp = qbase + (size_t)mt * 64 * 640;

    // ---- QK^T swapped: acc[j][r] = S^T[n = j*16+lg*4+r][m = m0+wvi*16+lr] ----
    f4v acc[8];
#pragma unroll
    for (int j = 0; j < 8; ++j) acc[j] = (f4v)0.0f;
#pragma unroll
    for (int ks = 0; ks < 3; ++ks) {
      const int ch = (ks * 4 + lg) * 8;
      s8v qv = (ch < 80) ? *(const s8v*)&qp[(size_t)lr * 640 + ch] : (s8v)(short)0;
#pragma unroll
      for (int j = 0; j < 8; ++j) {
        s8v kv = *(const s8v*)&kT[(j * 16 + lr) * 104 + ch];
        acc[j] = mfma16(kv, qv, acc[j]);   // A = K (n-rows), B = Q (m-rows)
      }
    }

    // ---- bias + in-lane softmax (row m = m0 + wvi*16 + lr) ----
    const int m_g = m0 + wvi * 16 + lr;
    const float gyc = ((float)(m_g >> 6) * 0.25f + (0.125f - 1.f)) * 3.75f;
    const float gxc = ((float)(m_g & 63) * 0.03125f + (0.015625f - 1.f)) * 31.75f;
    float mx = -1e30f;
#pragma unroll
    for (int j = 0; j < 8; ++j) {
      f4v pyv = *(const f4v*)&pynL[j * 16 + lg * 4];
      f4v pxv = *(const f4v*)&pxnL[j * 16 + lg * 4];
#pragma unroll
      for (int r = 0; r < 4; ++r) {
        float gy = gyc + pyv[r], gx = gxc + pxv[r];
        float fy = floorf(gy), fx = floorf(gx);
        int iy = (int)fy, ix = (int)fx;
        float wy = gy - fy, wx = gx - fx;
        const float* t = &rpeL[iy * 132 + ix];
        float t00 = t[0], t01 = t[1], t10 = t[132], t11 = t[133];
        float top = fmaf(wx, t01 - t00, t00);
        float bot = fmaf(wx, t11 - t10, t10);
        float bias = fmaf(wy, bot - top, top);
        float sv = fmaf(acc[j][r], scale, bias);
        acc[j][r] = sv;
        mx = fmaxf(mx, sv);
      }
    }
    mx = fmaxf(mx, __shfl_xor(mx, 16));
    mx = fmaxf(mx, __shfl_xor(mx, 32));
    float sm = 0.f;
#pragma unroll
    for (int j = 0; j < 8; ++j)
#pragma unroll
      for (int r = 0; r < 4; ++r) {
        float e = __expf(acc[j][r] - mx);
        acc[j][r] = e;
        sm += e;
      }
    sm += __shfl_xor(sm, 16);
    sm += __shfl_xor(sm, 32);
    const float inv = 1.f / sm;
    // P write: row m = wvi*16+lr, 4 consecutive n per j -> b64 writes
#pragma unroll
    for (int j = 0; j < 8; ++j) {
      s4v pk;
#pragma unroll
      for (int r = 0; r < 4; ++r) pk[r] = f2b(acc[j][r] * inv);
      *(s4v*)&pT[(wvi * 16 + lr) * 136 + j * 16 + lg * 4] = pk;
    }

    // ---- PV: P + V from LDS (same-wave RAW on pT) ----
    f4v pacc[5];
#pragma unroll
    for (int t = 0; t < 5; ++t) pacc[t] = (f4v)0.0f;
#pragma unroll
    for (int ks = 0; ks < 4; ++ks) {
      s8v pa = *(const s8v*)&pT[(wvi * 16 + lr) * 136 + ks * 32 + lg * 8];
#pragma unroll
      for (int ct = 0; ct < 5; ++ct) {
        s8v vb = *(const s8v*)&vT[(ct * 16 + lr) * 136 + ks * 32 + lg * 8];
        pacc[ct] = mfma16(pa, vb, pacc[ct]);
      }
    }
    short* aop = aobase + (size_t)mt * 64 * 640;
#pragma unroll
    for (int ct = 0; ct < 5; ++ct)
#pragma unroll
      for (int r = 0; r < 4; ++r)
        aop[(size_t)(lg * 4 + r) * 640 + ct * 16 + lr] = f2b(pacc[ct][r]);
  }
}

// =============================== launcher ===============================
extern "C" void kernel_launch(void* const* d_in, const int* in_sizes, int n_in,
                              void* d_out, int out_size, void* d_ws, size_t ws_size,
                              hipStream_t stream) {
  (void)in_sizes; (void)n_in; (void)out_size; (void)ws_size;
  const float* x   = (const float*)d_in[0];
  const float* y   = (const float*)d_in[1];
  const float* w1  = (const float*)d_in[2];
  const float* b1  = (const float*)d_in[3];
  const float* lng = (const float*)d_in[4];
  const float* lnb = (const float*)d_in[5];
  const float* w2  = (const float*)d_in[6];
  const float* qw  = (const float*)d_in[7];
  const float* qb  = (const float*)d_in[8];
  const float* kw  = (const float*)d_in[9];
  const float* kb  = (const float*)d_in[10];
  const float* vw  = (const float*)d_in[11];
  const float* vb  = (const float*)d_in[12];
  const float* ow  = (const float*)d_in[13];
  const float* ob  = (const float*)d_in[14];
  const float* rpe = (const float*)d_in[15];
  float* out = (float*)d_out;
  float* pos_out = out + 10485760;
  float* ref_out = out + 10518528;

  char* base = (char*)d_ws;
  size_t off = 0;
  auto take = [&](size_t bytes) {
    char* pch = base + off;
    off = (off + bytes + 255) & ~(size_t)255;
    return pch;
  };
  float* pos   = (float*)take(131072);        // [128][128][2] f32
  short* x_t   = (short*)take(20971520);      // [32][512][640] bf16
  short* y_t   = (short*)take(20971520);      // [32][512][640] bf16
  short* q_t   = (short*)take(20971520);      // [32][512][640] bf16
  short* qw_bf = (short*)take(819200);
  short* kw_bf = (short*)take(819200);
  short* vw_bf = (short*)take(819200);
  short* ow_bf = (short*)take(819200);
  short* xs_bf = (short*)take(5242880);       // [32][128][640] bf16
  short* k_t   = (short*)take(5242880);       // [32][128][640] bf16
  short* v_bf  = (short*)take(5242880);       // [32][640][128] bf16
  char*  regB  = take(20971520);              // co (f32 [128][128][320]) then ao_t
  float* co    = (float*)regB;
  short* ao_t  = (short*)regB;                // [32][512][640] bf16

  // transposes (x and y in one launch) + batched weight converts
  transpose_k<<<dim3(20, 16, 64), dim3(32, 8), 0, stream>>>(x, y, x_t, y_t);
  cvtw4_k<<<dim3(1600, 4), 256, 0, stream>>>(qw, kw, vw, ow, qw_bf, kw_bf, vw_bf, ow_bf);

  // offset network
  conv_off_k<<<dim3(40, 128), 256, 0, stream>>>(x, y, w1, b1, co);
  ln_proj_k<<<dim3(32, 128), 256, 0, stream>>>(co, lng, lnb, w2, pos, pos_out, ref_out);

  // deformable sampling
  sample_k<<<dim3(16, 128), 256, 0, stream>>>(x_t, pos, xs_bf);

  // projections (128^2-tile global_load_lds GEMMs; all operands [row][K])
  gemm128_k<true,  false><<<dim3(4, 5, 32), 256, 0, stream>>>(y_t, 512LL * 640, qw_bf, 0LL, qb, q_t, 512, 640, 640);
  gemm128_k<true,  false><<<dim3(1, 5, 32), 256, 0, stream>>>(xs_bf, 128LL * 640, kw_bf, 0LL, kb, k_t, 128, 640, 640);
  gemm128_k<false, false><<<dim3(5, 1, 32), 256, 0, stream>>>(vw_bf, 0LL, xs_bf, 128LL * 640, vb, v_bf, 640, 640, 128);

  // fused attention (QK^T + bias + softmax + PV); 512 blocks, 4 m-tiles each
  qkpv_k<<<dim3(256, 2), 256, 0, stream>>>(q_t, k_t, v_bf, pos, rpe, ao_t);

  // output projection (f32 out)
  gemm128_k<false, true><<<dim3(5, 4, 32), 256, 0, stream>>>(ow_bf, 0LL, ao_t, 512LL * 640, ob, out, 640, 640, 512);
}